// Round 8
// baseline (607.093 us; speedup 1.0000x reference)
//
#include <hip/hip_runtime.h>
#include <hip/hip_bf16.h>
#include <math.h>

// Problem constants
#define B_   16
#define P_   32
#define N_   1024
#define C_   192
#define H_   12
#define HD_  16
#define HID_ 768
#define C3_  576
#define SCALE_ 0.25f

using u16 = unsigned short;
typedef __bf16 bf16x8 __attribute__((ext_vector_type(8)));
typedef float f32x4 __attribute__((ext_vector_type(4)));
typedef u16 u16x8 __attribute__((ext_vector_type(8)));
typedef u16 u16x4 __attribute__((ext_vector_type(4)));

#define MFMA16(a, b, c) __builtin_amdgcn_mfma_f32_16x16x32_bf16((a), (b), (c), 0, 0, 0)

__device__ __forceinline__ int swz(int r) { return (r + (r >> 2)) & 3; }

__device__ __forceinline__ void splitf(float v, u16& h, u16& l) {
  union { __hip_bfloat16 b; u16 u; } c1, c2;
  c1.b = __float2bfloat16(v);
  float hv = __bfloat162float(c1.b);
  c2.b = __float2bfloat16(v - hv);
  h = c1.u; l = c2.u;
}

__device__ __forceinline__ u16 bfbits(float v) {
  union { __hip_bfloat16 b; u16 u; } c; c.b = __float2bfloat16(v); return c.u;
}

// LDS fragment read: tile stored as [row][32 k] u16, 64B rows, chunk-XOR swizzle.
__device__ __forceinline__ bf16x8 ldfrag(const u16* base, int row, int g) {
  return __builtin_bit_cast(bf16x8,
      *(const u16x8*)(base + row * 32 + ((g ^ swz(row)) << 3)));
}

__device__ __forceinline__ bf16x8 ldg8(const u16* p) {
  return __builtin_bit_cast(bf16x8, *(const u16x8*)p);
}

// ---------------------------------------------------------------------------
// Pack x -> zero-padded 34x34 image, [b][pad_pixel][192ch] bf16 hi/lo.
__global__ __launch_bounds__(256) void pack_x_kernel(const float* __restrict__ x,
                                                     u16* __restrict__ xph,
                                                     u16* __restrict__ xpl) {
  int tid = blockIdx.x * 256 + threadIdx.x;   // 16*1156*24 = 443904 total
  int b = tid / 27744;
  int r = tid - b * 27744;
  int pp = r / 24;
  int cg = (r - pp * 24) * 8;
  int pr = pp / 34, pc = pp - pr * 34;
  float v[8] = {0.f, 0.f, 0.f, 0.f, 0.f, 0.f, 0.f, 0.f};
  if (pr >= 1 && pr <= 32 && pc >= 1 && pc <= 32) {
    const float* src = x + ((size_t)b * N_ + (pr - 1) * 32 + (pc - 1)) * C_ + cg;
    float4 v0 = *(const float4*)src;
    float4 v1 = *(const float4*)(src + 4);
    v[0] = v0.x; v[1] = v0.y; v[2] = v0.z; v[3] = v0.w;
    v[4] = v1.x; v[5] = v1.y; v[6] = v1.z; v[7] = v1.w;
  }
  u16x8 vh, vl;
#pragma unroll
  for (int i = 0; i < 8; ++i) { u16 h, l; splitf(v[i], h, l); vh[i] = h; vl[i] = l; }
  size_t o = ((size_t)b * 1156 + pp) * C_ + cg;
  *(u16x8*)&xph[o] = vh;
  *(u16x8*)&xpl[o] = vl;
}

// Pack w1 [768][192][3][3] -> [tap][768][192] hi/lo
__global__ __launch_bounds__(256) void pack_w1_kernel(const float* __restrict__ w1,
                                                      u16* __restrict__ w1h,
                                                      u16* __restrict__ w1l) {
  int tid = blockIdx.x * 256 + threadIdx.x;   // 147456
  int oc = tid / C_, ic = tid - oc * C_;
  const float* src = w1 + ((size_t)oc * C_ + ic) * 9;
#pragma unroll
  for (int t9 = 0; t9 < 9; ++t9) {
    u16 h, l; splitf(src[t9], h, l);
    size_t o = (size_t)t9 * (HID_ * C_) + oc * C_ + ic;
    w1h[o] = h; w1l[o] = l;
  }
}

// Generic elementwise pack
__global__ __launch_bounds__(256) void pack_gen_kernel(const float* __restrict__ src,
                                                       u16* __restrict__ dh,
                                                       u16* __restrict__ dl, int n8) {
  int tid = blockIdx.x * 256 + threadIdx.x;
  if (tid >= n8) return;
  const float* s = src + (size_t)tid * 8;
  float4 v0 = *(const float4*)s;
  float4 v1 = *(const float4*)(s + 4);
  float v[8] = {v0.x, v0.y, v0.z, v0.w, v1.x, v1.y, v1.z, v1.w};
  u16x8 vh, vl;
#pragma unroll
  for (int i = 0; i < 8; ++i) { u16 h, l; splitf(v[i], h, l); vh[i] = h; vl[i] = l; }
  *(u16x8*)&dh[(size_t)tid * 8] = vh;
  *(u16x8*)&dl[(size_t)tid * 8] = vl;
}

// ---------------------------------------------------------------------------
// conv3x3 implicit GEMM. Block 128oc x 128px, 4 waves (2m x 2n).
// ks(6) outer: stage 204-px halo (6 pad rows x 34 cols x 32ch, hi/lo) once;
// taps(9) inner, barrier-free: weights direct from global (L2), pixels from halo LDS.
// grid (8, 6, 16).
__global__ __launch_bounds__(256, 3) void conv_mfma_kernel(
    const u16* __restrict__ xph, const u16* __restrict__ xpl,
    const u16* __restrict__ w1h, const u16* __restrict__ w1l,
    const float* __restrict__ b1, u16* __restrict__ a1h, u16* __restrict__ a1l) {
  __shared__ u16 sH[2][204 * 32];   // halo tile hi/lo, 26KB
  int t = threadIdx.x;
  int n0 = blockIdx.x * 128, oc0 = blockIdx.y * 128, b = blockIdx.z;
  int row0 = blockIdx.x * 4;        // first image row of this px-tile
  int wid = t >> 6, lane = t & 63;
  int wm = wid >> 1, wn = wid & 1;
  int g = lane >> 4, lr = lane & 15;
  f32x4 acc[4][4] = {};

  for (int ks = 0; ks < 6; ++ks) {
    int kk = ks * 32;
    __syncthreads();
    // stage halo: pad pixels [row0*34, row0*34 + 204), 32 ch, hi+lo
    for (int c = t; c < 1632; c += 256) {
      int plane = c >= 816;
      int rem = c - plane * 816;
      int px = rem >> 2, p = rem & 3;
      size_t gidx = ((size_t)b * 1156 + row0 * 34 + px) * C_ + kk + p * 8;
      const u16* src = plane ? xpl : xph;
      *(u16x8*)&sH[plane][px * 32 + ((p ^ swz(px)) << 3)] = *(const u16x8*)&src[gidx];
    }
    __syncthreads();

    for (int tap = 0; tap < 9; ++tap) {
      int dy = tap / 3, dx = tap - dy * 3;
      const u16* wth = w1h + (size_t)tap * (HID_ * C_) + kk + g * 8;
      const u16* wtl = w1l + (size_t)tap * (HID_ * C_) + kk + g * 8;
      bf16x8 ah[4], al[4], bh[4], bl[4];
#pragma unroll
      for (int mf = 0; mf < 4; ++mf) {
        size_t arow = (size_t)(oc0 + wm * 64 + mf * 16 + lr) * C_;
        ah[mf] = ldg8(wth + arow);
        al[mf] = ldg8(wtl + arow);
      }
#pragma unroll
      for (int nf = 0; nf < 4; ++nf) {
        int lp = wn * 64 + nf * 16 + lr;
        int hpx = ((lp >> 5) + dy) * 34 + (lp & 31) + dx;
        bh[nf] = ldfrag(&sH[0][0], hpx, g);
        bl[nf] = ldfrag(&sH[1][0], hpx, g);
      }
#pragma unroll
      for (int mf = 0; mf < 4; ++mf)
#pragma unroll
        for (int nf = 0; nf < 4; ++nf) {
          acc[mf][nf] = MFMA16(ah[mf], bh[nf], acc[mf][nf]);
          acc[mf][nf] = MFMA16(al[mf], bh[nf], acc[mf][nf]);
          acc[mf][nf] = MFMA16(ah[mf], bl[nf], acc[mf][nf]);
        }
    }
  }
#pragma unroll
  for (int mf = 0; mf < 4; ++mf)
#pragma unroll
    for (int nf = 0; nf < 4; ++nf) {
      int pix = n0 + wn * 64 + nf * 16 + lr;
      int oc = oc0 + wm * 64 + mf * 16 + g * 4;
      size_t oidx = ((size_t)b * N_ + pix) * HID_ + oc;
      u16x4 vh, vl;
#pragma unroll
      for (int r = 0; r < 4; ++r) {
        float v = acc[mf][nf][r] + b1[oc + r];
        v = v > 0.f ? v : 0.f;
        u16 h, l; splitf(v, h, l);
        vh[r] = h; vl[r] = l;
      }
      *(u16x4*)&a1h[oidx] = vh;
      *(u16x4*)&a1l[oidx] = vl;
    }
}

// ---------------------------------------------------------------------------
// Generic MFMA GEMM over [pixel][IC] activations. Block tile MT x 128px,
// 4 waves (2m x 2n). Weights (A) direct from global; B staged in LDS.
// grid (8, OC/MT, 16). ACT: 0 relu->bf16 hi/lo, 1 sigmoid->f32, 2 none->f32.
template <int ACT, int MT>
__global__ __launch_bounds__(256) void gemm_mfma_kernel(
    const u16* __restrict__ Wh, const u16* __restrict__ Wl,
    const float* __restrict__ bias,
    const u16* __restrict__ inh, const u16* __restrict__ inl,
    void* __restrict__ out0, void* __restrict__ out1, int OC, int IC) {
  constexpr int MF = MT / 32;
  __shared__ u16 sB[2][128 * 32];
  int t = threadIdx.x;
  int n0 = blockIdx.x * 128, oc0 = blockIdx.y * MT, b = blockIdx.z;
  int wid = t >> 6, lane = t & 63;
  int wm = wid >> 1, wn = wid & 1;
  int g = lane >> 4, lr = lane & 15;
  const u16* inbh = inh + (size_t)b * N_ * IC;
  const u16* inbl = inl + (size_t)b * N_ * IC;
  f32x4 acc[MF][4] = {};

  for (int ks = 0; ks < IC / 32; ++ks) {
    int kk = ks * 32;
    __syncthreads();
#pragma unroll
    for (int i = 0; i < 2; ++i) {
      int c = t + i * 256;
      int r = c >> 2, p = c & 3;
      size_t gidx = (size_t)(n0 + r) * IC + kk + p * 8;
      int lidx = r * 32 + ((p ^ swz(r)) << 3);
      *(u16x8*)&sB[0][lidx] = *(const u16x8*)&inbh[gidx];
      *(u16x8*)&sB[1][lidx] = *(const u16x8*)&inbl[gidx];
    }
    __syncthreads();
    bf16x8 ah[MF], al[MF], bh[4], bl[4];
#pragma unroll
    for (int mf = 0; mf < MF; ++mf) {
      size_t ai = (size_t)(oc0 + wm * (MT / 2) + mf * 16 + lr) * IC + kk + g * 8;
      ah[mf] = ldg8(&Wh[ai]);
      al[mf] = ldg8(&Wl[ai]);
    }
#pragma unroll
    for (int nf = 0; nf < 4; ++nf) {
      int row = wn * 64 + nf * 16 + lr;
      bh[nf] = ldfrag(&sB[0][0], row, g);
      bl[nf] = ldfrag(&sB[1][0], row, g);
    }
#pragma unroll
    for (int mf = 0; mf < MF; ++mf)
#pragma unroll
      for (int nf = 0; nf < 4; ++nf) {
        acc[mf][nf] = MFMA16(ah[mf], bh[nf], acc[mf][nf]);
        acc[mf][nf] = MFMA16(al[mf], bh[nf], acc[mf][nf]);
        acc[mf][nf] = MFMA16(ah[mf], bl[nf], acc[mf][nf]);
      }
  }
#pragma unroll
  for (int mf = 0; mf < MF; ++mf)
#pragma unroll
    for (int nf = 0; nf < 4; ++nf) {
      int pix = n0 + wn * 64 + nf * 16 + lr;
      int oc = oc0 + wm * (MT / 2) + mf * 16 + g * 4;
      size_t oidx = ((size_t)b * N_ + pix) * OC + oc;
      if constexpr (ACT == 0) {
        u16x4 vh, vl;
#pragma unroll
        for (int r = 0; r < 4; ++r) {
          float v = acc[mf][nf][r] + bias[oc + r];
          v = v > 0.f ? v : 0.f;
          u16 h, l; splitf(v, h, l);
          vh[r] = h; vl[r] = l;
        }
        *(u16x4*)&((u16*)out0)[oidx] = vh;
        *(u16x4*)&((u16*)out1)[oidx] = vl;
      } else if constexpr (ACT == 1) {
        float4 res;
        float r0 = acc[mf][nf][0] + bias[oc + 0];
        float r1 = acc[mf][nf][1] + bias[oc + 1];
        float r2 = acc[mf][nf][2] + bias[oc + 2];
        float r3 = acc[mf][nf][3] + bias[oc + 3];
        res.x = 1.f / (1.f + __expf(-r0)); res.y = 1.f / (1.f + __expf(-r1));
        res.z = 1.f / (1.f + __expf(-r2)); res.w = 1.f / (1.f + __expf(-r3));
        *(float4*)&((float*)out0)[oidx] = res;
      } else {
        float4 res;
        res.x = acc[mf][nf][0]; res.y = acc[mf][nf][1];
        res.z = acc[mf][nf][2]; res.w = acc[mf][nf][3];
        *(float4*)&((float*)out0)[oidx] = res;
      }
    }
}

// ---------------------------------------------------------------------------
// qkv gather: a3 [b][pixel][576] f32 -> QH/QL/KH/KL (bf16 hi/lo) + VB (bf16)
// in [b,h,n,16] u16 layout. Same flat-index scramble as reference.
__global__ __launch_bounds__(256) void qkv_gather_kernel(const float* __restrict__ a3,
                                                         const float* __restrict__ x,
                                                         u16* __restrict__ qh,
                                                         u16* __restrict__ ql,
                                                         u16* __restrict__ kh,
                                                         u16* __restrict__ kl,
                                                         u16* __restrict__ vb) {
  int idx = blockIdx.x * 256 + threadIdx.x;
  int b = idx / 196608;
  int gg = idx - b * 196608;
  int m = gg & 1023, cc = gg >> 10;
  int j = m * 192 + cc;
  float y = x[((size_t)b * N_ + (j & 1023)) * C_ + (j >> 10)];
  int n2 = gg / 192;
  int hd = gg - n2 * 192;
  size_t out_idx = (((size_t)b * H_ + (hd >> 4)) * N_ + n2) * HD_ + (hd & 15);
  const float* a3b = a3 + (size_t)b * (C3_ * N_);
  int jk = j + 196608, jv = j + 393216;
  int nq = j / 576,  chq = j - nq * 576;
  int nk = jk / 576, chk = jk - nk * 576;
  int nv = jv / 576, chv = jv - nv * 576;
  float aq = a3b[(size_t)nq * C3_ + chq];
  float ak = a3b[(size_t)nk * C3_ + chk];
  float av = a3b[(size_t)nv * C3_ + chv];
  u16 hh, ll;
  splitf(aq * y * SCALE_, hh, ll); qh[out_idx] = hh; ql[out_idx] = ll;
  splitf(ak * y, hh, ll);          kh[out_idx] = hh; kl[out_idx] = ll;
  vb[out_idx] = bfbits(av * y);
}

// ---------------------------------------------------------------------------
// MFMA flash attention. grid (16 qtiles, 12 h, 16 b), 4 waves x 16 q-rows.
// 128-key chunks (8 iters). Swapped QK^T (S^T[key,q], d padded 16->32) and
// swapped PV (O^T[d,q]). Q/K hi/lo bf16 (3-mfma), P/V single bf16.
__global__ __launch_bounds__(256) void attn_mfma_kernel(
    const u16* __restrict__ QH, const u16* __restrict__ QL,
    const u16* __restrict__ KH, const u16* __restrict__ KL,
    const u16* __restrict__ VB, u16* __restrict__ oh, u16* __restrict__ ol) {
  __shared__ u16 sKH[128 * 32];   // [key][32 d-padded] swizzled, hi (8KB)
  __shared__ u16 sKL[128 * 32];   // lo (8KB)
  __shared__ u16 sVT[16 * 128];   // [d][128 keys], 16B-chunk XOR swizzle (4KB)
  __shared__ u16 sP[4][16 * 128]; // per-wave P^T bounce [q][128 keys] (16KB)
  int t = threadIdx.x;
  int qt = blockIdx.x, h = blockIdx.y, b = blockIdx.z;
  int wid = t >> 6, lane = t & 63;
  int lr = lane & 15, g = lane >> 4;
  size_t base = ((size_t)(b * H_ + h)) * (N_ * HD_);
  int qrow = qt * 64 + wid * 16 + lr;

  // zero the d=16..31 pad chunks of sKH/sKL once (swizzle-consistent positions)
  {
    int plane = t >> 7, r = t & 127;
    u16* dst = (plane ? sKL : sKH) + r * 32;
    u16x8 z = {};
    *(u16x8*)(dst + ((2 ^ swz(r)) << 3)) = z;
    *(u16x8*)(dst + ((3 ^ swz(r)) << 3)) = z;
  }

  // Q fragments (held in registers): lane lr = q-col, g = d-slice (g>=2 zero)
  bf16x8 qfh = {}, qfl = {};
  if (g < 2) {
    size_t qi = base + (size_t)qrow * HD_ + g * 8;
    qfh = __builtin_bit_cast(bf16x8, *(const u16x8*)&QH[qi]);
    qfl = __builtin_bit_cast(bf16x8, *(const u16x8*)&QL[qi]);
  }

  f32x4 acc = {};
  float mrun = -1e30f, lrun = 0.f;
  u16* pw = &sP[wid][0];

  for (int ch = 0; ch < 8; ++ch) {
    int key0 = ch * 128;
    __syncthreads();
    // ---- stage K chunk (hi: t<128, lo: t>=128), 128 keys x 16 real d ----
    {
      int plane = t >> 7, id = t & 127;
      const u16* kbase = (plane ? KL : KH) + base;
      u16* dstb = plane ? sKL : sKH;
#pragma unroll
      for (int i = 0; i < 2; ++i) {
        int e = i * 128 + id;
        int r = e >> 1, gg2 = e & 1;
        *(u16x8*)&dstb[r * 32 + ((gg2 ^ swz(r)) << 3)] =
            *(const u16x8*)&kbase[(size_t)(key0 + r) * HD_ + gg2 * 8];
      }
    }
    // ---- stage V^T: [d][128 keys] via u16 scatter ----
#pragma unroll
    for (int i = 0; i < 2; ++i) {
      int e = i * 256 + t;
      int key = e >> 2, d0 = (e & 3) * 4;
      u16x4 vv = *(const u16x4*)&VB[base + (size_t)(key0 + key) * HD_ + d0];
#pragma unroll
      for (int jj = 0; jj < 4; ++jj) {
        int d = d0 + jj;
        sVT[d * 128 + (((key >> 3) ^ (d & 7)) << 3) + (key & 7)] = vv[jj];
      }
    }
    __syncthreads();

    // ---- QK^T: 8 key-subtiles, S^T[key,q], hi/lo 3-mfma ----
    f32x4 st[8];
#pragma unroll
    for (int t8 = 0; t8 < 8; ++t8) {
      bf16x8 kfh = ldfrag(sKH, t8 * 16 + lr, g);
      bf16x8 kfl = ldfrag(sKL, t8 * 16 + lr, g);
      f32x4 s = {};
      s = MFMA16(kfh, qfl, s);
      s = MFMA16(kfl, qfh, s);
      s = MFMA16(kfh, qfh, s);
      st[t8] = s;
    }

    // ---- online softmax: lane owns q=lr; keys split over 4 lanes (g) ----
    float cmax = -1e30f;
#pragma unroll
    for (int t8 = 0; t8 < 8; ++t8)
#pragma unroll
      for (int r = 0; r < 4; ++r) cmax = fmaxf(cmax, st[t8][r]);
    cmax = fmaxf(cmax, __shfl_xor(cmax, 16));
    cmax = fmaxf(cmax, __shfl_xor(cmax, 32));
    float mnew = fmaxf(mrun, cmax);
    float corr = __expf(mrun - mnew);
    float p[32];
    float psum = 0.f;
#pragma unroll
    for (int t8 = 0; t8 < 8; ++t8)
#pragma unroll
      for (int r = 0; r < 4; ++r) {
        float pv = __expf(st[t8][r] - mnew);
        p[t8 * 4 + r] = pv; psum += pv;
      }
    psum += __shfl_xor(psum, 16);
    psum += __shfl_xor(psum, 32);
    lrun = lrun * corr + psum;
    mrun = mnew;
#pragma unroll
    for (int r = 0; r < 4; ++r) acc[r] *= corr;

    // ---- pack P to bf16, bounce via per-wave LDS to re-group keys ----
#pragma unroll
    for (int t8 = 0; t8 < 8; ++t8) {
      unsigned w0 = (unsigned)bfbits(p[t8 * 4 + 0]) | ((unsigned)bfbits(p[t8 * 4 + 1]) << 16);
      unsigned w1 = (unsigned)bfbits(p[t8 * 4 + 2]) | ((unsigned)bfbits(p[t8 * 4 + 3]) << 16);
      int c = 2 * t8 + (g >> 1);
      int off = lr * 128 + ((c ^ (lr & 7)) << 3) + (g & 1) * 4;  // u16 units
      uint2 val; val.x = w0; val.y = w1;
      *(uint2*)&pw[off] = val;
    }
    // ---- PV: O^T += V^T-frag x P^T-frag, 4 key-subtiles of 32 ----
#pragma unroll
    for (int kk = 0; kk < 4; ++kk) {
      int off = lr * 128 + (((kk * 4 + g) ^ (lr & 7)) << 3);
      bf16x8 pb = __builtin_bit_cast(bf16x8, *(const u16x8*)&pw[off]);
      bf16x8 va = __builtin_bit_cast(bf16x8, *(const u16x8*)&sVT[off]);
      acc = MFMA16(va, pb, acc);
    }
  }

  // ---- epilogue: lane owns q=lr, d = 4g + reg ----
  float inv = 1.0f / lrun;
  size_t o = ((size_t)b * N_ + qrow) * C_ + h * HD_ + 4 * g;
  u16x4 vh, vl;
#pragma unroll
  for (int r = 0; r < 4; ++r) {
    u16 hh, ll; splitf(acc[r] * inv, hh, ll);
    vh[r] = hh; vl[r] = ll;
  }
  *(u16x4*)&oh[o] = vh;
  *(u16x4*)&ol[o] = vl;
}

// ---------------------------------------------------------------------------
extern "C" void kernel_launch(void* const* d_in, const int* in_sizes, int n_in,
                              void* d_out, int out_size, void* d_ws, size_t ws_size,
                              hipStream_t stream) {
  const float* x     = (const float*)d_in[0];
  const float* w1    = (const float*)d_in[1];
  const float* b1    = (const float*)d_in[2];
  const float* w2    = (const float*)d_in[3];
  const float* b2    = (const float*)d_in[4];
  const float* w3    = (const float*)d_in[5];
  const float* b3    = (const float*)d_in[6];
  const float* w_out = (const float*)d_in[7];
  float* out = (float*)d_out;

  // ---- workspace layout (byte offsets) ----
  char* ws = (char*)d_ws;
  u16* XPH = (u16*)(ws + 0);                    //  7,102,464 B
  u16* XPL = (u16*)(ws + 7102464);
  u16* W1H = (u16*)(ws + 14204928);             //  2,654,208 B
  u16* W1L = (u16*)(ws + 16859136);
  u16* W2H = (u16*)(ws + 19513344);             //  1,179,648 B
  u16* W2L = (u16*)(ws + 20692992);
  u16* W3H = (u16*)(ws + 21872640);             //    884,736 B
  u16* W3L = (u16*)(ws + 22757376);
  u16* WOH = (u16*)(ws + 23642112);             //     73,728 B
  u16* WOL = (u16*)(ws + 23715840);
  // Region A @23,789,568: a1 hi/lo -> a3 f32 -> o hi/lo
  u16*   A1H = (u16*)(ws + 23789568);
  u16*   A1L = (u16*)(ws + 48955392);
  float* A3  = (float*)(ws + 23789568);         // a1 dead
  u16*   OH  = (u16*)(ws + 23789568);           // a3 dead after gather
  u16*   OL  = (u16*)(ws + 36372480);
  // Region B @74,121,216: a2 hi/lo -> QH/QL/KH/KL/VB u16 (6,291,456 B each)
  u16*   A2H = (u16*)(ws + 74121216);
  u16*   A2L = (u16*)(ws + 99287040);
  u16*   QHb = (u16*)(ws + 74121216);           // a2 dead
  u16*   QLb = (u16*)(ws + 80412672);
  u16*   KHb = (u16*)(ws + 86704128);
  u16*   KLb = (u16*)(ws + 92995584);
  u16*   VBb = (u16*)(ws + 99287040);
  // total: 124,452,864 B

  // ---- pack inputs to bf16 hi/lo ----
  pack_x_kernel<<<dim3(1734), 256, 0, stream>>>(x, XPH, XPL);
  pack_w1_kernel<<<dim3(576), 256, 0, stream>>>(w1, W1H, W1L);
  pack_gen_kernel<<<dim3(288), 256, 0, stream>>>(w2, W2H, W2L, 73728);
  pack_gen_kernel<<<dim3(216), 256, 0, stream>>>(w3, W3H, W3L, 55296);
  pack_gen_kernel<<<dim3(18), 256, 0, stream>>>(w_out, WOH, WOL, 4608);

  // ---- main pipeline ----
  conv_mfma_kernel<<<dim3(8, 6, 16), 256, 0, stream>>>(XPH, XPL, W1H, W1L, b1, A1H, A1L);
  gemm_mfma_kernel<0, 128><<<dim3(8, 6, 16), 256, 0, stream>>>(
      W2H, W2L, b2, A1H, A1L, A2H, A2L, HID_, HID_);
  gemm_mfma_kernel<1, 64><<<dim3(8, 9, 16), 256, 0, stream>>>(
      W3H, W3L, b3, A2H, A2L, A3, nullptr, C3_, HID_);
  qkv_gather_kernel<<<dim3(12288), 256, 0, stream>>>(A3, x, QHb, QLb, KHb, KLb, VBb);
  attn_mfma_kernel<<<dim3(16, 12, 16), 256, 0, stream>>>(QHb, QLb, KHb, KLb, VBb, OH, OL);
  gemm_mfma_kernel<2, 64><<<dim3(8, 3, 16), 256, 0, stream>>>(
      WOH, WOL, nullptr, OH, OL, out, nullptr, C_, C_);
}

// Round 10
// 509.350 us; speedup vs baseline: 1.1919x; 1.1919x over previous
//
#include <hip/hip_runtime.h>
#include <hip/hip_bf16.h>
#include <math.h>

// Problem constants
#define B_   16
#define P_   32
#define N_   1024
#define C_   192
#define H_   12
#define HD_  16
#define HID_ 768
#define C3_  576
#define SCALE_ 0.25f

using u16 = unsigned short;
typedef __bf16 bf16x8 __attribute__((ext_vector_type(8)));
typedef float f32x4 __attribute__((ext_vector_type(4)));
typedef u16 u16x8 __attribute__((ext_vector_type(8)));
typedef u16 u16x4 __attribute__((ext_vector_type(4)));

#define MFMA16(a, b, c) __builtin_amdgcn_mfma_f32_16x16x32_bf16((a), (b), (c), 0, 0, 0)

__device__ __forceinline__ int swz(int r) { return (r + (r >> 2)) & 3; }

__device__ __forceinline__ void splitf(float v, u16& h, u16& l) {
  union { __hip_bfloat16 b; u16 u; } c1, c2;
  c1.b = __float2bfloat16(v);
  float hv = __bfloat162float(c1.b);
  c2.b = __float2bfloat16(v - hv);
  h = c1.u; l = c2.u;
}

__device__ __forceinline__ u16 bfbits(float v) {
  union { __hip_bfloat16 b; u16 u; } c; c.b = __float2bfloat16(v); return c.u;
}

// LDS fragment read: tile stored as [row][32 k] u16, 64B rows, chunk-XOR swizzle.
__device__ __forceinline__ bf16x8 ldfrag(const u16* base, int row, int g) {
  return __builtin_bit_cast(bf16x8,
      *(const u16x8*)(base + row * 32 + ((g ^ swz(row)) << 3)));
}

// ---------------------------------------------------------------------------
// Pack x -> zero-padded 34x34 image, [b][pad_pixel][192ch] bf16 hi/lo.
__global__ __launch_bounds__(256) void pack_x_kernel(const float* __restrict__ x,
                                                     u16* __restrict__ xph,
                                                     u16* __restrict__ xpl) {
  int tid = blockIdx.x * 256 + threadIdx.x;   // 16*1156*24 = 443904 total
  int b = tid / 27744;
  int r = tid - b * 27744;
  int pp = r / 24;
  int cg = (r - pp * 24) * 8;
  int pr = pp / 34, pc = pp - pr * 34;
  float v[8] = {0.f, 0.f, 0.f, 0.f, 0.f, 0.f, 0.f, 0.f};
  if (pr >= 1 && pr <= 32 && pc >= 1 && pc <= 32) {
    const float* src = x + ((size_t)b * N_ + (pr - 1) * 32 + (pc - 1)) * C_ + cg;
    float4 v0 = *(const float4*)src;
    float4 v1 = *(const float4*)(src + 4);
    v[0] = v0.x; v[1] = v0.y; v[2] = v0.z; v[3] = v0.w;
    v[4] = v1.x; v[5] = v1.y; v[6] = v1.z; v[7] = v1.w;
  }
  u16x8 vh, vl;
#pragma unroll
  for (int i = 0; i < 8; ++i) { u16 h, l; splitf(v[i], h, l); vh[i] = h; vl[i] = l; }
  size_t o = ((size_t)b * 1156 + pp) * C_ + cg;
  *(u16x8*)&xph[o] = vh;
  *(u16x8*)&xpl[o] = vl;
}

// Pack w1 [768][192][3][3] -> [tap][768][192] hi/lo
__global__ __launch_bounds__(256) void pack_w1_kernel(const float* __restrict__ w1,
                                                      u16* __restrict__ w1h,
                                                      u16* __restrict__ w1l) {
  int tid = blockIdx.x * 256 + threadIdx.x;   // 147456
  int oc = tid / C_, ic = tid - oc * C_;
  const float* src = w1 + ((size_t)oc * C_ + ic) * 9;
#pragma unroll
  for (int t9 = 0; t9 < 9; ++t9) {
    u16 h, l; splitf(src[t9], h, l);
    size_t o = (size_t)t9 * (HID_ * C_) + oc * C_ + ic;
    w1h[o] = h; w1l[o] = l;
  }
}

// Generic elementwise pack
__global__ __launch_bounds__(256) void pack_gen_kernel(const float* __restrict__ src,
                                                       u16* __restrict__ dh,
                                                       u16* __restrict__ dl, int n8) {
  int tid = blockIdx.x * 256 + threadIdx.x;
  if (tid >= n8) return;
  const float* s = src + (size_t)tid * 8;
  float4 v0 = *(const float4*)s;
  float4 v1 = *(const float4*)(s + 4);
  float v[8] = {v0.x, v0.y, v0.z, v0.w, v1.x, v1.y, v1.z, v1.w};
  u16x8 vh, vl;
#pragma unroll
  for (int i = 0; i < 8; ++i) { u16 h, l; splitf(v[i], h, l); vh[i] = h; vl[i] = l; }
  *(u16x8*)&dh[(size_t)tid * 8] = vh;
  *(u16x8*)&dl[(size_t)tid * 8] = vl;
}

// ---------------------------------------------------------------------------
// conv3x3 implicit GEMM. Block 128oc x 128px, 4 waves (2m x 2n).
// ks(6) outer: stage 204-px halo once per ks (B for all 9 taps).
// taps(9) inner: A (weights) double-buffered in LDS; tap t+1's A loads issued
// into registers BEFORE tap t's MFMA cluster (latency hidden), ds_written to
// the other buffer after, ONE barrier per tap. grid (8, 6, 16), 2 blocks/CU.
__global__ __launch_bounds__(256, 2) void conv_mfma_kernel(
    const u16* __restrict__ xph, const u16* __restrict__ xpl,
    const u16* __restrict__ w1h, const u16* __restrict__ w1l,
    const float* __restrict__ b1, u16* __restrict__ a1h, u16* __restrict__ a1l) {
  __shared__ u16 sH[2][204 * 32];     // halo pixels hi/lo (25.5 KB)
  __shared__ u16 sA[2][2][128 * 32];  // weights [buf][plane] (32 KB)
  int t = threadIdx.x;
  int n0 = blockIdx.x * 128, oc0 = blockIdx.y * 128, b = blockIdx.z;
  int row0 = blockIdx.x * 4;          // first image row of this px-tile
  int wid = t >> 6, lane = t & 63;
  int wm = wid >> 1, wn = wid & 1;
  int g = lane >> 4, lr = lane & 15;
  // per-thread A-staging slots (2 x 16B per plane)
  int r0s = t >> 2, p0s = t & 3;
  int r1s = (t + 256) >> 2, p1s = t & 3;  // (t+256)&3 == t&3
  size_t ga0 = (size_t)(oc0 + r0s) * C_ + p0s * 8;
  size_t ga1 = (size_t)(oc0 + r1s) * C_ + p1s * 8;
  int la0 = r0s * 32 + ((p0s ^ swz(r0s)) << 3);
  int la1 = r1s * 32 + ((p1s ^ swz(r1s)) << 3);
  f32x4 acc[4][4] = {};
  int cur = 0;

  for (int ks = 0; ks < 6; ++ks) {
    int kk = ks * 32;
    // ---- stage halo: pad pixels [row0*34, row0*34+204), 32ch, hi+lo ----
    for (int c = t; c < 1632; c += 256) {
      int plane = c >= 816;
      int rem = c - plane * 816;
      int px = rem >> 2, p = rem & 3;
      size_t gidx = ((size_t)b * 1156 + row0 * 34 + px) * C_ + kk + p * 8;
      const u16* src = plane ? xpl : xph;
      *(u16x8*)&sH[plane][px * 32 + ((p ^ swz(px)) << 3)] = *(const u16x8*)&src[gidx];
    }
    // ---- stage A for tap 0 into sA[cur] ----
    {
      const u16* wth = w1h + kk;
      const u16* wtl = w1l + kk;
      *(u16x8*)&sA[cur][0][la0] = *(const u16x8*)&wth[ga0];
      *(u16x8*)&sA[cur][0][la1] = *(const u16x8*)&wth[ga1];
      *(u16x8*)&sA[cur][1][la0] = *(const u16x8*)&wtl[ga0];
      *(u16x8*)&sA[cur][1][la1] = *(const u16x8*)&wtl[ga1];
    }
    __syncthreads();

    for (int tap = 0; tap < 9; ++tap) {
      // issue next tap's A loads early (hidden under this tap's MFMAs)
      u16x8 rh0, rh1, rl0, rl1;
      if (tap < 8) {
        const u16* wth = w1h + (size_t)(tap + 1) * (HID_ * C_) + kk;
        const u16* wtl = w1l + (size_t)(tap + 1) * (HID_ * C_) + kk;
        rh0 = *(const u16x8*)&wth[ga0];
        rh1 = *(const u16x8*)&wth[ga1];
        rl0 = *(const u16x8*)&wtl[ga0];
        rl1 = *(const u16x8*)&wtl[ga1];
      }
      int dy = tap / 3, dx = tap - dy * 3;
      bf16x8 ah[4], al[4], bh[4], bl[4];
#pragma unroll
      for (int mf = 0; mf < 4; ++mf) {
        int row = wm * 64 + mf * 16 + lr;
        ah[mf] = ldfrag(&sA[cur][0][0], row, g);
        al[mf] = ldfrag(&sA[cur][1][0], row, g);
      }
#pragma unroll
      for (int nf = 0; nf < 4; ++nf) {
        int lp = wn * 64 + nf * 16 + lr;
        int hpx = ((lp >> 5) + dy) * 34 + (lp & 31) + dx;
        bh[nf] = ldfrag(&sH[0][0], hpx, g);
        bl[nf] = ldfrag(&sH[1][0], hpx, g);
      }
#pragma unroll
      for (int mf = 0; mf < 4; ++mf)
#pragma unroll
        for (int nf = 0; nf < 4; ++nf) {
          acc[mf][nf] = MFMA16(ah[mf], bh[nf], acc[mf][nf]);
          acc[mf][nf] = MFMA16(al[mf], bh[nf], acc[mf][nf]);
          acc[mf][nf] = MFMA16(ah[mf], bl[nf], acc[mf][nf]);
        }
      // write next tap's A into the other buffer (disjoint from reads above)
      if (tap < 8) {
        *(u16x8*)&sA[cur ^ 1][0][la0] = rh0;
        *(u16x8*)&sA[cur ^ 1][0][la1] = rh1;
        *(u16x8*)&sA[cur ^ 1][1][la0] = rl0;
        *(u16x8*)&sA[cur ^ 1][1][la1] = rl1;
      }
      __syncthreads();
      cur ^= 1;
    }
  }
#pragma unroll
  for (int mf = 0; mf < 4; ++mf)
#pragma unroll
    for (int nf = 0; nf < 4; ++nf) {
      int pix = n0 + wn * 64 + nf * 16 + lr;
      int oc = oc0 + wm * 64 + mf * 16 + g * 4;
      size_t oidx = ((size_t)b * N_ + pix) * HID_ + oc;
      u16x4 vh, vl;
#pragma unroll
      for (int r = 0; r < 4; ++r) {
        float v = acc[mf][nf][r] + b1[oc + r];
        v = v > 0.f ? v : 0.f;
        u16 h, l; splitf(v, h, l);
        vh[r] = h; vl[r] = l;
      }
      *(u16x4*)&a1h[oidx] = vh;
      *(u16x4*)&a1l[oidx] = vl;
    }
}

// ---------------------------------------------------------------------------
// Generic MFMA GEMM over [pixel][IC] activations. Block tile MT x 128px,
// 4 waves (2m x 2n), wave tile (MT/2) x 64. grid (8, OC/MT, 16).
// (Round-4 proven form: A and B both staged in LDS.)
// ACT: 0 relu->bf16 hi/lo, 1 sigmoid->f32, 2 none->f32.
template <int ACT, int MT>
__global__ __launch_bounds__(256) void gemm_mfma_kernel(
    const u16* __restrict__ Wh, const u16* __restrict__ Wl,
    const float* __restrict__ bias,
    const u16* __restrict__ inh, const u16* __restrict__ inl,
    void* __restrict__ out0, void* __restrict__ out1, int OC, int IC) {
  constexpr int MF = MT / 32;
  __shared__ u16 sA[2][MT * 32];
  __shared__ u16 sB[2][128 * 32];
  int t = threadIdx.x;
  int n0 = blockIdx.x * 128, oc0 = blockIdx.y * MT, b = blockIdx.z;
  int wid = t >> 6, lane = t & 63;
  int wm = wid >> 1, wn = wid & 1;
  int g = lane >> 4, lr = lane & 15;
  const u16* inbh = inh + (size_t)b * N_ * IC;
  const u16* inbl = inl + (size_t)b * N_ * IC;
  f32x4 acc[MF][4] = {};

  for (int ks = 0; ks < IC / 32; ++ks) {
    int kk = ks * 32;
    __syncthreads();
    for (int c = t; c < MT * 4; c += 256) {
      int r = c >> 2, p = c & 3;
      size_t gidx = (size_t)(oc0 + r) * IC + kk + p * 8;
      int lidx = r * 32 + ((p ^ swz(r)) << 3);
      *(u16x8*)&sA[0][lidx] = *(const u16x8*)&Wh[gidx];
      *(u16x8*)&sA[1][lidx] = *(const u16x8*)&Wl[gidx];
    }
#pragma unroll
    for (int i = 0; i < 2; ++i) {
      int c = t + i * 256;
      int r = c >> 2, p = c & 3;
      size_t gidx = (size_t)(n0 + r) * IC + kk + p * 8;
      int lidx = r * 32 + ((p ^ swz(r)) << 3);
      *(u16x8*)&sB[0][lidx] = *(const u16x8*)&inbh[gidx];
      *(u16x8*)&sB[1][lidx] = *(const u16x8*)&inbl[gidx];
    }
    __syncthreads();
    bf16x8 ah[MF], al[MF], bh[4], bl[4];
#pragma unroll
    for (int mf = 0; mf < MF; ++mf) {
      int row = wm * (MT / 2) + mf * 16 + lr;
      ah[mf] = ldfrag(&sA[0][0], row, g);
      al[mf] = ldfrag(&sA[1][0], row, g);
    }
#pragma unroll
    for (int nf = 0; nf < 4; ++nf) {
      int row = wn * 64 + nf * 16 + lr;
      bh[nf] = ldfrag(&sB[0][0], row, g);
      bl[nf] = ldfrag(&sB[1][0], row, g);
    }
#pragma unroll
    for (int mf = 0; mf < MF; ++mf)
#pragma unroll
      for (int nf = 0; nf < 4; ++nf) {
        acc[mf][nf] = MFMA16(ah[mf], bh[nf], acc[mf][nf]);
        acc[mf][nf] = MFMA16(al[mf], bh[nf], acc[mf][nf]);
        acc[mf][nf] = MFMA16(ah[mf], bl[nf], acc[mf][nf]);
      }
  }
#pragma unroll
  for (int mf = 0; mf < MF; ++mf)
#pragma unroll
    for (int nf = 0; nf < 4; ++nf) {
      int pix = n0 + wn * 64 + nf * 16 + lr;
      int oc = oc0 + wm * (MT / 2) + mf * 16 + g * 4;
      size_t oidx = ((size_t)b * N_ + pix) * OC + oc;
      if constexpr (ACT == 0) {
        u16x4 vh, vl;
#pragma unroll
        for (int r = 0; r < 4; ++r) {
          float v = acc[mf][nf][r] + bias[oc + r];
          v = v > 0.f ? v : 0.f;
          u16 h, l; splitf(v, h, l);
          vh[r] = h; vl[r] = l;
        }
        *(u16x4*)&((u16*)out0)[oidx] = vh;
        *(u16x4*)&((u16*)out1)[oidx] = vl;
      } else if constexpr (ACT == 1) {
        float4 res;
        float r0 = acc[mf][nf][0] + bias[oc + 0];
        float r1 = acc[mf][nf][1] + bias[oc + 1];
        float r2 = acc[mf][nf][2] + bias[oc + 2];
        float r3 = acc[mf][nf][3] + bias[oc + 3];
        res.x = 1.f / (1.f + __expf(-r0)); res.y = 1.f / (1.f + __expf(-r1));
        res.z = 1.f / (1.f + __expf(-r2)); res.w = 1.f / (1.f + __expf(-r3));
        *(float4*)&((float*)out0)[oidx] = res;
      } else {
        float4 res;
        res.x = acc[mf][nf][0]; res.y = acc[mf][nf][1];
        res.z = acc[mf][nf][2]; res.w = acc[mf][nf][3];
        *(float4*)&((float*)out0)[oidx] = res;
      }
    }
}

// ---------------------------------------------------------------------------
// qkv gather: a3 [b][pixel][576] f32 -> QH/QL/KH/KL (bf16 hi/lo) + VB (bf16)
// in [b,h,n,16] u16 layout. Same flat-index scramble as reference.
__global__ __launch_bounds__(256) void qkv_gather_kernel(const float* __restrict__ a3,
                                                         const float* __restrict__ x,
                                                         u16* __restrict__ qh,
                                                         u16* __restrict__ ql,
                                                         u16* __restrict__ kh,
                                                         u16* __restrict__ kl,
                                                         u16* __restrict__ vb) {
  int idx = blockIdx.x * 256 + threadIdx.x;
  int b = idx / 196608;
  int gg = idx - b * 196608;
  int m = gg & 1023, cc = gg >> 10;
  int j = m * 192 + cc;
  float y = x[((size_t)b * N_ + (j & 1023)) * C_ + (j >> 10)];
  int n2 = gg / 192;
  int hd = gg - n2 * 192;
  size_t out_idx = (((size_t)b * H_ + (hd >> 4)) * N_ + n2) * HD_ + (hd & 15);
  const float* a3b = a3 + (size_t)b * (C3_ * N_);
  int jk = j + 196608, jv = j + 393216;
  int nq = j / 576,  chq = j - nq * 576;
  int nk = jk / 576, chk = jk - nk * 576;
  int nv = jv / 576, chv = jv - nv * 576;
  float aq = a3b[(size_t)nq * C3_ + chq];
  float ak = a3b[(size_t)nk * C3_ + chk];
  float av = a3b[(size_t)nv * C3_ + chv];
  u16 hh, ll;
  splitf(aq * y * SCALE_, hh, ll); qh[out_idx] = hh; ql[out_idx] = ll;
  splitf(ak * y, hh, ll);          kh[out_idx] = hh; kl[out_idx] = ll;
  vb[out_idx] = bfbits(av * y);
}

// ---------------------------------------------------------------------------
// MFMA flash attention. grid (16 qtiles, 12 h, 16 b), 4 waves x 16 q-rows.
// 128-key chunks (8 iters). Swapped QK^T (S^T[key,q], d padded 16->32) and
// swapped PV (O^T[d,q]). Q/K hi/lo bf16 (3-mfma), P/V single bf16.
__global__ __launch_bounds__(256) void attn_mfma_kernel(
    const u16* __restrict__ QH, const u16* __restrict__ QL,
    const u16* __restrict__ KH, const u16* __restrict__ KL,
    const u16* __restrict__ VB, u16* __restrict__ oh, u16* __restrict__ ol) {
  __shared__ u16 sKH[128 * 32];   // [key][32 d-padded] swizzled, hi (8KB)
  __shared__ u16 sKL[128 * 32];   // lo (8KB)
  __shared__ u16 sVT[16 * 128];   // [d][128 keys], 16B-chunk XOR swizzle (4KB)
  __shared__ u16 sP[4][16 * 128]; // per-wave P^T bounce [q][128 keys] (16KB)
  int t = threadIdx.x;
  int qt = blockIdx.x, h = blockIdx.y, b = blockIdx.z;
  int wid = t >> 6, lane = t & 63;
  int lr = lane & 15, g = lane >> 4;
  size_t base = ((size_t)(b * H_ + h)) * (N_ * HD_);
  int qrow = qt * 64 + wid * 16 + lr;

  // zero the d=16..31 pad chunks of sKH/sKL once (swizzle-consistent positions)
  {
    int plane = t >> 7, r = t & 127;
    u16* dst = (plane ? sKL : sKH) + r * 32;
    u16x8 z = {};
    *(u16x8*)(dst + ((2 ^ swz(r)) << 3)) = z;
    *(u16x8*)(dst + ((3 ^ swz(r)) << 3)) = z;
  }

  // Q fragments (held in registers): lane lr = q-col, g = d-slice (g>=2 zero)
  bf16x8 qfh = {}, qfl = {};
  if (g < 2) {
    size_t qi = base + (size_t)qrow * HD_ + g * 8;
    qfh = __builtin_bit_cast(bf16x8, *(const u16x8*)&QH[qi]);
    qfl = __builtin_bit_cast(bf16x8, *(const u16x8*)&QL[qi]);
  }

  f32x4 acc = {};
  float mrun = -1e30f, lrun = 0.f;
  u16* pw = &sP[wid][0];

  for (int ch = 0; ch < 8; ++ch) {
    int key0 = ch * 128;
    __syncthreads();
    // ---- stage K chunk (hi: t<128, lo: t>=128), 128 keys x 16 real d ----
    {
      int plane = t >> 7, id = t & 127;
      const u16* kbase = (plane ? KL : KH) + base;
      u16* dstb = plane ? sKL : sKH;
#pragma unroll
      for (int i = 0; i < 2; ++i) {
        int e = i * 128 + id;
        int r = e >> 1, gg2 = e & 1;
        *(u16x8*)&dstb[r * 32 + ((gg2 ^ swz(r)) << 3)] =
            *(const u16x8*)&kbase[(size_t)(key0 + r) * HD_ + gg2 * 8];
      }
    }
    // ---- stage V^T: [d][128 keys] via u16 scatter ----
#pragma unroll
    for (int i = 0; i < 2; ++i) {
      int e = i * 256 + t;
      int key = e >> 2, d0 = (e & 3) * 4;
      u16x4 vv = *(const u16x4*)&VB[base + (size_t)(key0 + key) * HD_ + d0];
#pragma unroll
      for (int jj = 0; jj < 4; ++jj) {
        int d = d0 + jj;
        sVT[d * 128 + (((key >> 3) ^ (d & 7)) << 3) + (key & 7)] = vv[jj];
      }
    }
    __syncthreads();

    // ---- QK^T: 8 key-subtiles, S^T[key,q], hi/lo 3-mfma ----
    f32x4 st[8];
#pragma unroll
    for (int t8 = 0; t8 < 8; ++t8) {
      bf16x8 kfh = ldfrag(sKH, t8 * 16 + lr, g);
      bf16x8 kfl = ldfrag(sKL, t8 * 16 + lr, g);
      f32x4 s = {};
      s = MFMA16(kfh, qfl, s);
      s = MFMA16(kfl, qfh, s);
      s = MFMA16(kfh, qfh, s);
      st[t8] = s;
    }

    // ---- online softmax: lane owns q=lr; keys split over 4 lanes (g) ----
    float cmax = -1e30f;
#pragma unroll
    for (int t8 = 0; t8 < 8; ++t8)
#pragma unroll
      for (int r = 0; r < 4; ++r) cmax = fmaxf(cmax, st[t8][r]);
    cmax = fmaxf(cmax, __shfl_xor(cmax, 16));
    cmax = fmaxf(cmax, __shfl_xor(cmax, 32));
    float mnew = fmaxf(mrun, cmax);
    float corr = __expf(mrun - mnew);
    float p[32];
    float psum = 0.f;
#pragma unroll
    for (int t8 = 0; t8 < 8; ++t8)
#pragma unroll
      for (int r = 0; r < 4; ++r) {
        float pv = __expf(st[t8][r] - mnew);
        p[t8 * 4 + r] = pv; psum += pv;
      }
    psum += __shfl_xor(psum, 16);
    psum += __shfl_xor(psum, 32);
    lrun = lrun * corr + psum;
    mrun = mnew;
#pragma unroll
    for (int r = 0; r < 4; ++r) acc[r] *= corr;

    // ---- pack P to bf16, bounce via per-wave LDS to re-group keys ----
#pragma unroll
    for (int t8 = 0; t8 < 8; ++t8) {
      unsigned w0 = (unsigned)bfbits(p[t8 * 4 + 0]) | ((unsigned)bfbits(p[t8 * 4 + 1]) << 16);
      unsigned w1 = (unsigned)bfbits(p[t8 * 4 + 2]) | ((unsigned)bfbits(p[t8 * 4 + 3]) << 16);
      int c = 2 * t8 + (g >> 1);
      int off = lr * 128 + ((c ^ (lr & 7)) << 3) + (g & 1) * 4;  // u16 units
      uint2 val; val.x = w0; val.y = w1;
      *(uint2*)&pw[off] = val;
    }
    // ---- PV: O^T += V^T-frag x P^T-frag, 4 key-subtiles of 32 ----
#pragma unroll
    for (int kk = 0; kk < 4; ++kk) {
      int off = lr * 128 + (((kk * 4 + g) ^ (lr & 7)) << 3);
      bf16x8 pb = __builtin_bit_cast(bf16x8, *(const u16x8*)&pw[off]);
      bf16x8 va = __builtin_bit_cast(bf16x8, *(const u16x8*)&sVT[off]);
      acc = MFMA16(va, pb, acc);
    }
  }

  // ---- epilogue: lane owns q=lr, d = 4g + reg ----
  float inv = 1.0f / lrun;
  size_t o = ((size_t)b * N_ + qrow) * C_ + h * HD_ + 4 * g;
  u16x4 vh, vl;
#pragma unroll
  for (int r = 0; r < 4; ++r) {
    u16 hh, ll; splitf(acc[r] * inv, hh, ll);
    vh[r] = hh; vl[r] = ll;
  }
  *(u16x4*)&oh[o] = vh;
  *(u16x4*)&ol[o] = vl;
}

// ---------------------------------------------------------------------------
extern "C" void kernel_launch(void* const* d_in, const int* in_sizes, int n_in,
                              void* d_out, int out_size, void* d_ws, size_t ws_size,
                              hipStream_t stream) {
  const float* x     = (const float*)d_in[0];
  const float* w1    = (const float*)d_in[1];
  const float* b1    = (const float*)d_in[2];
  const float* w2    = (const float*)d_in[3];
  const float* b2    = (const float*)d_in[4];
  const float* w3    = (const float*)d_in[5];
  const float* b3    = (const float*)d_in[6];
  const float* w_out = (const float*)d_in[7];
  float* out = (float*)d_out;

  // ---- workspace layout (byte offsets) ----
  char* ws = (char*)d_ws;
  u16* XPH = (u16*)(ws + 0);                    //  7,102,464 B
  u16* XPL = (u16*)(ws + 7102464);
  u16* W1H = (u16*)(ws + 14204928);             //  2,654,208 B
  u16* W1L = (u16*)(ws + 16859136);
  u16* W2H = (u16*)(ws + 19513344);             //  1,179,648 B
  u16* W2L = (u16*)(ws + 20692992);
  u16* W3H = (u16*)(ws + 21872640);             //    884,736 B
  u16* W3L = (u16*)(ws + 22757376);
  u16* WOH = (u16*)(ws + 23642112);             //     73,728 B
  u16* WOL = (u16*)(ws + 23715840);
  // Region A @23,789,568: a1 hi/lo -> a3 f32 -> o hi/lo
  u16*   A1H = (u16*)(ws + 23789568);
  u16*   A1L = (u16*)(ws + 48955392);
  float* A3  = (float*)(ws + 23789568);         // a1 dead
  u16*   OH  = (u16*)(ws + 23789568);           // a3 dead after gather
  u16*   OL  = (u16*)(ws + 36372480);
  // Region B @74,121,216: a2 hi/lo -> QH/QL/KH/KL/VB u16 (6,291,456 B each)
  u16*   A2H = (u16*)(ws + 74121216);
  u16*   A2L = (u16*)(ws + 99287040);
  u16*   QHb = (u16*)(ws + 74121216);           // a2 dead
  u16*   QLb = (u16*)(ws + 80412672);
  u16*   KHb = (u16*)(ws + 86704128);
  u16*   KLb = (u16*)(ws + 92995584);
  u16*   VBb = (u16*)(ws + 99287040);
  // total: 124,452,864 B

  // ---- pack inputs to bf16 hi/lo ----
  pack_x_kernel<<<dim3(1734), 256, 0, stream>>>(x, XPH, XPL);
  pack_w1_kernel<<<dim3(576), 256, 0, stream>>>(w1, W1H, W1L);
  pack_gen_kernel<<<dim3(288), 256, 0, stream>>>(w2, W2H, W2L, 73728);
  pack_gen_kernel<<<dim3(216), 256, 0, stream>>>(w3, W3H, W3L, 55296);
  pack_gen_kernel<<<dim3(18), 256, 0, stream>>>(w_out, WOH, WOL, 4608);

  // ---- main pipeline ----
  conv_mfma_kernel<<<dim3(8, 6, 16), 256, 0, stream>>>(XPH, XPL, W1H, W1L, b1, A1H, A1L);
  gemm_mfma_kernel<0, 128><<<dim3(8, 6, 16), 256, 0, stream>>>(
      W2H, W2L, b2, A1H, A1L, A2H, A2L, HID_, HID_);
  gemm_mfma_kernel<1, 64><<<dim3(8, 9, 16), 256, 0, stream>>>(
      W3H, W3L, b3, A2H, A2L, A3, nullptr, C3_, HID_);
  qkv_gather_kernel<<<dim3(12288), 256, 0, stream>>>(A3, x, QHb, QLb, KHb, KLb, VBb);
  attn_mfma_kernel<<<dim3(16, 12, 16), 256, 0, stream>>>(QHb, QLb, KHb, KLb, VBb, OH, OL);
  gemm_mfma_kernel<2, 64><<<dim3(8, 3, 16), 256, 0, stream>>>(
      WOH, WOL, nullptr, OH, OL, out, nullptr, C_, C_);
}

// Round 11
// 482.664 us; speedup vs baseline: 1.2578x; 1.0553x over previous
//
#include <hip/hip_runtime.h>
#include <hip/hip_bf16.h>
#include <math.h>

// Problem constants
#define B_   16
#define P_   32
#define N_   1024
#define C_   192
#define H_   12
#define HD_  16
#define HID_ 768
#define C3_  576
#define SCALE_ 0.25f

using u16 = unsigned short;
typedef __bf16 bf16x8 __attribute__((ext_vector_type(8)));
typedef float f32x4 __attribute__((ext_vector_type(4)));
typedef u16 u16x8 __attribute__((ext_vector_type(8)));
typedef u16 u16x4 __attribute__((ext_vector_type(4)));

#define MFMA16(a, b, c) __builtin_amdgcn_mfma_f32_16x16x32_bf16((a), (b), (c), 0, 0, 0)

__device__ __forceinline__ int swz(int r) { return (r + (r >> 2)) & 3; }

__device__ __forceinline__ void splitf(float v, u16& h, u16& l) {
  union { __hip_bfloat16 b; u16 u; } c1, c2;
  c1.b = __float2bfloat16(v);
  float hv = __bfloat162float(c1.b);
  c2.b = __float2bfloat16(v - hv);
  h = c1.u; l = c2.u;
}

__device__ __forceinline__ u16 bfbits(float v) {
  union { __hip_bfloat16 b; u16 u; } c; c.b = __float2bfloat16(v); return c.u;
}

// LDS fragment read: tile stored as [row][32 k] u16, 64B rows, chunk-XOR swizzle.
__device__ __forceinline__ bf16x8 ldfrag(const u16* base, int row, int g) {
  return __builtin_bit_cast(bf16x8,
      *(const u16x8*)(base + row * 32 + ((g ^ swz(row)) << 3)));
}

// ---------------------------------------------------------------------------
// Pack x -> zero-padded 34x34 image, [b][pad_pixel][192ch] bf16 hi/lo.
__global__ __launch_bounds__(256) void pack_x_kernel(const float* __restrict__ x,
                                                     u16* __restrict__ xph,
                                                     u16* __restrict__ xpl) {
  int tid = blockIdx.x * 256 + threadIdx.x;   // 16*1156*24 = 443904 total
  int b = tid / 27744;
  int r = tid - b * 27744;
  int pp = r / 24;
  int cg = (r - pp * 24) * 8;
  int pr = pp / 34, pc = pp - pr * 34;
  float v[8] = {0.f, 0.f, 0.f, 0.f, 0.f, 0.f, 0.f, 0.f};
  if (pr >= 1 && pr <= 32 && pc >= 1 && pc <= 32) {
    const float* src = x + ((size_t)b * N_ + (pr - 1) * 32 + (pc - 1)) * C_ + cg;
    float4 v0 = *(const float4*)src;
    float4 v1 = *(const float4*)(src + 4);
    v[0] = v0.x; v[1] = v0.y; v[2] = v0.z; v[3] = v0.w;
    v[4] = v1.x; v[5] = v1.y; v[6] = v1.z; v[7] = v1.w;
  }
  u16x8 vh, vl;
#pragma unroll
  for (int i = 0; i < 8; ++i) { u16 h, l; splitf(v[i], h, l); vh[i] = h; vl[i] = l; }
  size_t o = ((size_t)b * 1156 + pp) * C_ + cg;
  *(u16x8*)&xph[o] = vh;
  *(u16x8*)&xpl[o] = vl;
}

// Pack w1 [768][192][3][3] -> [tap][768][192] hi/lo
__global__ __launch_bounds__(256) void pack_w1_kernel(const float* __restrict__ w1,
                                                      u16* __restrict__ w1h,
                                                      u16* __restrict__ w1l) {
  int tid = blockIdx.x * 256 + threadIdx.x;   // 147456
  int oc = tid / C_, ic = tid - oc * C_;
  const float* src = w1 + ((size_t)oc * C_ + ic) * 9;
#pragma unroll
  for (int t9 = 0; t9 < 9; ++t9) {
    u16 h, l; splitf(src[t9], h, l);
    size_t o = (size_t)t9 * (HID_ * C_) + oc * C_ + ic;
    w1h[o] = h; w1l[o] = l;
  }
}

// Generic elementwise pack
__global__ __launch_bounds__(256) void pack_gen_kernel(const float* __restrict__ src,
                                                       u16* __restrict__ dh,
                                                       u16* __restrict__ dl, int n8) {
  int tid = blockIdx.x * 256 + threadIdx.x;
  if (tid >= n8) return;
  const float* s = src + (size_t)tid * 8;
  float4 v0 = *(const float4*)s;
  float4 v1 = *(const float4*)(s + 4);
  float v[8] = {v0.x, v0.y, v0.z, v0.w, v1.x, v1.y, v1.z, v1.w};
  u16x8 vh, vl;
#pragma unroll
  for (int i = 0; i < 8; ++i) { u16 h, l; splitf(v[i], h, l); vh[i] = h; vl[i] = l; }
  *(u16x8*)&dh[(size_t)tid * 8] = vh;
  *(u16x8*)&dl[(size_t)tid * 8] = vl;
}

// ---------------------------------------------------------------------------
// conv3x3 implicit GEMM. Block 128oc x 128px, 4 waves (2m x 2n).
// ks(6) outer: stage 204-px halo once per ks (B for all 9 taps).
// taps(9) inner: A (weights) SINGLE-buffered in LDS (42.5KB total -> 3 blocks/CU);
// tap t+1's A loads issued into regs at top of tap t's MFMA cluster (L2 latency
// hidden), written to sA between two barriers after the cluster.
// grid (8, 6, 16) = 768 blocks = exactly 3/CU.
__global__ __launch_bounds__(256, 3) void conv_mfma_kernel(
    const u16* __restrict__ xph, const u16* __restrict__ xpl,
    const u16* __restrict__ w1h, const u16* __restrict__ w1l,
    const float* __restrict__ b1, u16* __restrict__ a1h, u16* __restrict__ a1l) {
  __shared__ u16 sH[2][204 * 32];   // halo pixels hi/lo (25.5 KB)
  __shared__ u16 sA[2][128 * 32];   // weights [plane], single buffer (16 KB)
  int t = threadIdx.x;
  int n0 = blockIdx.x * 128, oc0 = blockIdx.y * 128, b = blockIdx.z;
  int row0 = blockIdx.x * 4;        // first image row of this px-tile
  int wid = t >> 6, lane = t & 63;
  int wm = wid >> 1, wn = wid & 1;
  int g = lane >> 4, lr = lane & 15;
  // per-thread A-staging slots (2 x 16B per plane)
  int r0s = t >> 2, p0s = t & 3;
  int r1s = 64 + (t >> 2);
  size_t ga0 = (size_t)(oc0 + r0s) * C_ + p0s * 8;
  size_t ga1 = (size_t)(oc0 + r1s) * C_ + p0s * 8;
  int la0 = r0s * 32 + ((p0s ^ swz(r0s)) << 3);
  int la1 = r1s * 32 + ((p0s ^ swz(r1s)) << 3);
  f32x4 acc[4][4] = {};

  for (int ks = 0; ks < 6; ++ks) {
    int kk = ks * 32;
    __syncthreads();   // previous iteration's reads of sH/sA complete
    // ---- stage halo: pad pixels [row0*34, row0*34+204), 32ch, hi+lo ----
    for (int c = t; c < 1632; c += 256) {
      int plane = c >= 816;
      int rem = c - plane * 816;
      int px = rem >> 2, p = rem & 3;
      size_t gidx = ((size_t)b * 1156 + row0 * 34 + px) * C_ + kk + p * 8;
      const u16* src = plane ? xpl : xph;
      *(u16x8*)&sH[plane][px * 32 + ((p ^ swz(px)) << 3)] = *(const u16x8*)&src[gidx];
    }
    // ---- stage A for tap 0 ----
    {
      const u16* wth = w1h + kk;
      const u16* wtl = w1l + kk;
      *(u16x8*)&sA[0][la0] = *(const u16x8*)&wth[ga0];
      *(u16x8*)&sA[0][la1] = *(const u16x8*)&wth[ga1];
      *(u16x8*)&sA[1][la0] = *(const u16x8*)&wtl[ga0];
      *(u16x8*)&sA[1][la1] = *(const u16x8*)&wtl[ga1];
    }
    __syncthreads();

    for (int tap = 0; tap < 9; ++tap) {
      // issue next tap's A loads early (latency hidden under this tap's MFMAs)
      u16x8 rh0, rh1, rl0, rl1;
      if (tap < 8) {
        const u16* wth = w1h + (size_t)(tap + 1) * (HID_ * C_) + kk;
        const u16* wtl = w1l + (size_t)(tap + 1) * (HID_ * C_) + kk;
        rh0 = *(const u16x8*)&wth[ga0];
        rh1 = *(const u16x8*)&wth[ga1];
        rl0 = *(const u16x8*)&wtl[ga0];
        rl1 = *(const u16x8*)&wtl[ga1];
      }
      int dy = tap / 3, dx = tap - dy * 3;
      bf16x8 ah[4], al[4], bh[4], bl[4];
#pragma unroll
      for (int mf = 0; mf < 4; ++mf) {
        int row = wm * 64 + mf * 16 + lr;
        ah[mf] = ldfrag(&sA[0][0], row, g);
        al[mf] = ldfrag(&sA[1][0], row, g);
      }
#pragma unroll
      for (int nf = 0; nf < 4; ++nf) {
        int lp = wn * 64 + nf * 16 + lr;
        int hpx = ((lp >> 5) + dy) * 34 + (lp & 31) + dx;
        bh[nf] = ldfrag(&sH[0][0], hpx, g);
        bl[nf] = ldfrag(&sH[1][0], hpx, g);
      }
#pragma unroll
      for (int mf = 0; mf < 4; ++mf)
#pragma unroll
        for (int nf = 0; nf < 4; ++nf) {
          acc[mf][nf] = MFMA16(ah[mf], bh[nf], acc[mf][nf]);
          acc[mf][nf] = MFMA16(al[mf], bh[nf], acc[mf][nf]);
          acc[mf][nf] = MFMA16(ah[mf], bl[nf], acc[mf][nf]);
        }
      if (tap < 8) {
        __syncthreads();   // all waves' sA reads for this tap complete
        *(u16x8*)&sA[0][la0] = rh0;
        *(u16x8*)&sA[0][la1] = rh1;
        *(u16x8*)&sA[1][la0] = rl0;
        *(u16x8*)&sA[1][la1] = rl1;
        __syncthreads();   // next tap's A visible
      }
    }
  }
#pragma unroll
  for (int mf = 0; mf < 4; ++mf)
#pragma unroll
    for (int nf = 0; nf < 4; ++nf) {
      int pix = n0 + wn * 64 + nf * 16 + lr;
      int oc = oc0 + wm * 64 + mf * 16 + g * 4;
      size_t oidx = ((size_t)b * N_ + pix) * HID_ + oc;
      u16x4 vh, vl;
#pragma unroll
      for (int r = 0; r < 4; ++r) {
        float v = acc[mf][nf][r] + b1[oc + r];
        v = v > 0.f ? v : 0.f;
        u16 h, l; splitf(v, h, l);
        vh[r] = h; vl[r] = l;
      }
      *(u16x4*)&a1h[oidx] = vh;
      *(u16x4*)&a1l[oidx] = vl;
    }
}

// ---------------------------------------------------------------------------
// Generic MFMA GEMM over [pixel][IC] activations. Block tile MT x 128px,
// 4 waves (2m x 2n), wave tile (MT/2) x 64. grid (8, OC/MT, 16).
// (Round-4 proven form: A and B both staged in LDS.)
// ACT: 0 relu->bf16 hi/lo, 1 sigmoid->f32, 2 none->f32.
template <int ACT, int MT>
__global__ __launch_bounds__(256) void gemm_mfma_kernel(
    const u16* __restrict__ Wh, const u16* __restrict__ Wl,
    const float* __restrict__ bias,
    const u16* __restrict__ inh, const u16* __restrict__ inl,
    void* __restrict__ out0, void* __restrict__ out1, int OC, int IC) {
  constexpr int MF = MT / 32;
  __shared__ u16 sA[2][MT * 32];
  __shared__ u16 sB[2][128 * 32];
  int t = threadIdx.x;
  int n0 = blockIdx.x * 128, oc0 = blockIdx.y * MT, b = blockIdx.z;
  int wid = t >> 6, lane = t & 63;
  int wm = wid >> 1, wn = wid & 1;
  int g = lane >> 4, lr = lane & 15;
  const u16* inbh = inh + (size_t)b * N_ * IC;
  const u16* inbl = inl + (size_t)b * N_ * IC;
  f32x4 acc[MF][4] = {};

  for (int ks = 0; ks < IC / 32; ++ks) {
    int kk = ks * 32;
    __syncthreads();
    for (int c = t; c < MT * 4; c += 256) {
      int r = c >> 2, p = c & 3;
      size_t gidx = (size_t)(oc0 + r) * IC + kk + p * 8;
      int lidx = r * 32 + ((p ^ swz(r)) << 3);
      *(u16x8*)&sA[0][lidx] = *(const u16x8*)&Wh[gidx];
      *(u16x8*)&sA[1][lidx] = *(const u16x8*)&Wl[gidx];
    }
#pragma unroll
    for (int i = 0; i < 2; ++i) {
      int c = t + i * 256;
      int r = c >> 2, p = c & 3;
      size_t gidx = (size_t)(n0 + r) * IC + kk + p * 8;
      int lidx = r * 32 + ((p ^ swz(r)) << 3);
      *(u16x8*)&sB[0][lidx] = *(const u16x8*)&inbh[gidx];
      *(u16x8*)&sB[1][lidx] = *(const u16x8*)&inbl[gidx];
    }
    __syncthreads();
    bf16x8 ah[MF], al[MF], bh[4], bl[4];
#pragma unroll
    for (int mf = 0; mf < MF; ++mf) {
      int row = wm * (MT / 2) + mf * 16 + lr;
      ah[mf] = ldfrag(&sA[0][0], row, g);
      al[mf] = ldfrag(&sA[1][0], row, g);
    }
#pragma unroll
    for (int nf = 0; nf < 4; ++nf) {
      int row = wn * 64 + nf * 16 + lr;
      bh[nf] = ldfrag(&sB[0][0], row, g);
      bl[nf] = ldfrag(&sB[1][0], row, g);
    }
#pragma unroll
    for (int mf = 0; mf < MF; ++mf)
#pragma unroll
      for (int nf = 0; nf < 4; ++nf) {
        acc[mf][nf] = MFMA16(ah[mf], bh[nf], acc[mf][nf]);
        acc[mf][nf] = MFMA16(al[mf], bh[nf], acc[mf][nf]);
        acc[mf][nf] = MFMA16(ah[mf], bl[nf], acc[mf][nf]);
      }
  }
#pragma unroll
  for (int mf = 0; mf < MF; ++mf)
#pragma unroll
    for (int nf = 0; nf < 4; ++nf) {
      int pix = n0 + wn * 64 + nf * 16 + lr;
      int oc = oc0 + wm * (MT / 2) + mf * 16 + g * 4;
      size_t oidx = ((size_t)b * N_ + pix) * OC + oc;
      if constexpr (ACT == 0) {
        u16x4 vh, vl;
#pragma unroll
        for (int r = 0; r < 4; ++r) {
          float v = acc[mf][nf][r] + bias[oc + r];
          v = v > 0.f ? v : 0.f;
          u16 h, l; splitf(v, h, l);
          vh[r] = h; vl[r] = l;
        }
        *(u16x4*)&((u16*)out0)[oidx] = vh;
        *(u16x4*)&((u16*)out1)[oidx] = vl;
      } else if constexpr (ACT == 1) {
        float4 res;
        float r0 = acc[mf][nf][0] + bias[oc + 0];
        float r1 = acc[mf][nf][1] + bias[oc + 1];
        float r2 = acc[mf][nf][2] + bias[oc + 2];
        float r3 = acc[mf][nf][3] + bias[oc + 3];
        res.x = 1.f / (1.f + __expf(-r0)); res.y = 1.f / (1.f + __expf(-r1));
        res.z = 1.f / (1.f + __expf(-r2)); res.w = 1.f / (1.f + __expf(-r3));
        *(float4*)&((float*)out0)[oidx] = res;
      } else {
        float4 res;
        res.x = acc[mf][nf][0]; res.y = acc[mf][nf][1];
        res.z = acc[mf][nf][2]; res.w = acc[mf][nf][3];
        *(float4*)&((float*)out0)[oidx] = res;
      }
    }
}

// ---------------------------------------------------------------------------
// qkv gather: a3 [b][pixel][576] f32 -> QH/QL/KH/KL (bf16 hi/lo) + VB (bf16)
// in [b,h,n,16] u16 layout. Same flat-index scramble as reference.
__global__ __launch_bounds__(256) void qkv_gather_kernel(const float* __restrict__ a3,
                                                         const float* __restrict__ x,
                                                         u16* __restrict__ qh,
                                                         u16* __restrict__ ql,
                                                         u16* __restrict__ kh,
                                                         u16* __restrict__ kl,
                                                         u16* __restrict__ vb) {
  int idx = blockIdx.x * 256 + threadIdx.x;
  int b = idx / 196608;
  int gg = idx - b * 196608;
  int m = gg & 1023, cc = gg >> 10;
  int j = m * 192 + cc;
  float y = x[((size_t)b * N_ + (j & 1023)) * C_ + (j >> 10)];
  int n2 = gg / 192;
  int hd = gg - n2 * 192;
  size_t out_idx = (((size_t)b * H_ + (hd >> 4)) * N_ + n2) * HD_ + (hd & 15);
  const float* a3b = a3 + (size_t)b * (C3_ * N_);
  int jk = j + 196608, jv = j + 393216;
  int nq = j / 576,  chq = j - nq * 576;
  int nk = jk / 576, chk = jk - nk * 576;
  int nv = jv / 576, chv = jv - nv * 576;
  float aq = a3b[(size_t)nq * C3_ + chq];
  float ak = a3b[(size_t)nk * C3_ + chk];
  float av = a3b[(size_t)nv * C3_ + chv];
  u16 hh, ll;
  splitf(aq * y * SCALE_, hh, ll); qh[out_idx] = hh; ql[out_idx] = ll;
  splitf(ak * y, hh, ll);          kh[out_idx] = hh; kl[out_idx] = ll;
  vb[out_idx] = bfbits(av * y);
}

// ---------------------------------------------------------------------------
// MFMA flash attention. grid (16 qtiles, 12 h, 16 b), 4 waves x 16 q-rows.
// 128-key chunks (8 iters). Swapped QK^T (S^T[key,q], d padded 16->32) and
// swapped PV (O^T[d,q]). Q/K hi/lo bf16 (3-mfma), P/V single bf16.
__global__ __launch_bounds__(256) void attn_mfma_kernel(
    const u16* __restrict__ QH, const u16* __restrict__ QL,
    const u16* __restrict__ KH, const u16* __restrict__ KL,
    const u16* __restrict__ VB, u16* __restrict__ oh, u16* __restrict__ ol) {
  __shared__ u16 sKH[128 * 32];   // [key][32 d-padded] swizzled, hi (8KB)
  __shared__ u16 sKL[128 * 32];   // lo (8KB)
  __shared__ u16 sVT[16 * 128];   // [d][128 keys], 16B-chunk XOR swizzle (4KB)
  __shared__ u16 sP[4][16 * 128]; // per-wave P^T bounce [q][128 keys] (16KB)
  int t = threadIdx.x;
  int qt = blockIdx.x, h = blockIdx.y, b = blockIdx.z;
  int wid = t >> 6, lane = t & 63;
  int lr = lane & 15, g = lane >> 4;
  size_t base = ((size_t)(b * H_ + h)) * (N_ * HD_);
  int qrow = qt * 64 + wid * 16 + lr;

  // zero the d=16..31 pad chunks of sKH/sKL once (swizzle-consistent positions)
  {
    int plane = t >> 7, r = t & 127;
    u16* dst = (plane ? sKL : sKH) + r * 32;
    u16x8 z = {};
    *(u16x8*)(dst + ((2 ^ swz(r)) << 3)) = z;
    *(u16x8*)(dst + ((3 ^ swz(r)) << 3)) = z;
  }

  // Q fragments (held in registers): lane lr = q-col, g = d-slice (g>=2 zero)
  bf16x8 qfh = {}, qfl = {};
  if (g < 2) {
    size_t qi = base + (size_t)qrow * HD_ + g * 8;
    qfh = __builtin_bit_cast(bf16x8, *(const u16x8*)&QH[qi]);
    qfl = __builtin_bit_cast(bf16x8, *(const u16x8*)&QL[qi]);
  }

  f32x4 acc = {};
  float mrun = -1e30f, lrun = 0.f;
  u16* pw = &sP[wid][0];

  for (int ch = 0; ch < 8; ++ch) {
    int key0 = ch * 128;
    __syncthreads();
    // ---- stage K chunk (hi: t<128, lo: t>=128), 128 keys x 16 real d ----
    {
      int plane = t >> 7, id = t & 127;
      const u16* kbase = (plane ? KL : KH) + base;
      u16* dstb = plane ? sKL : sKH;
#pragma unroll
      for (int i = 0; i < 2; ++i) {
        int e = i * 128 + id;
        int r = e >> 1, gg2 = e & 1;
        *(u16x8*)&dstb[r * 32 + ((gg2 ^ swz(r)) << 3)] =
            *(const u16x8*)&kbase[(size_t)(key0 + r) * HD_ + gg2 * 8];
      }
    }
    // ---- stage V^T: [d][128 keys] via u16 scatter ----
#pragma unroll
    for (int i = 0; i < 2; ++i) {
      int e = i * 256 + t;
      int key = e >> 2, d0 = (e & 3) * 4;
      u16x4 vv = *(const u16x4*)&VB[base + (size_t)(key0 + key) * HD_ + d0];
#pragma unroll
      for (int jj = 0; jj < 4; ++jj) {
        int d = d0 + jj;
        sVT[d * 128 + (((key >> 3) ^ (d & 7)) << 3) + (key & 7)] = vv[jj];
      }
    }
    __syncthreads();

    // ---- QK^T: 8 key-subtiles, S^T[key,q], hi/lo 3-mfma ----
    f32x4 st[8];
#pragma unroll
    for (int t8 = 0; t8 < 8; ++t8) {
      bf16x8 kfh = ldfrag(sKH, t8 * 16 + lr, g);
      bf16x8 kfl = ldfrag(sKL, t8 * 16 + lr, g);
      f32x4 s = {};
      s = MFMA16(kfh, qfl, s);
      s = MFMA16(kfl, qfh, s);
      s = MFMA16(kfh, qfh, s);
      st[t8] = s;
    }

    // ---- online softmax: lane owns q=lr; keys split over 4 lanes (g) ----
    float cmax = -1e30f;
#pragma unroll
    for (int t8 = 0; t8 < 8; ++t8)
#pragma unroll
      for (int r = 0; r < 4; ++r) cmax = fmaxf(cmax, st[t8][r]);
    cmax = fmaxf(cmax, __shfl_xor(cmax, 16));
    cmax = fmaxf(cmax, __shfl_xor(cmax, 32));
    float mnew = fmaxf(mrun, cmax);
    float corr = __expf(mrun - mnew);
    float p[32];
    float psum = 0.f;
#pragma unroll
    for (int t8 = 0; t8 < 8; ++t8)
#pragma unroll
      for (int r = 0; r < 4; ++r) {
        float pv = __expf(st[t8][r] - mnew);
        p[t8 * 4 + r] = pv; psum += pv;
      }
    psum += __shfl_xor(psum, 16);
    psum += __shfl_xor(psum, 32);
    lrun = lrun * corr + psum;
    mrun = mnew;
#pragma unroll
    for (int r = 0; r < 4; ++r) acc[r] *= corr;

    // ---- pack P to bf16, bounce via per-wave LDS to re-group keys ----
#pragma unroll
    for (int t8 = 0; t8 < 8; ++t8) {
      unsigned w0 = (unsigned)bfbits(p[t8 * 4 + 0]) | ((unsigned)bfbits(p[t8 * 4 + 1]) << 16);
      unsigned w1 = (unsigned)bfbits(p[t8 * 4 + 2]) | ((unsigned)bfbits(p[t8 * 4 + 3]) << 16);
      int c = 2 * t8 + (g >> 1);
      int off = lr * 128 + ((c ^ (lr & 7)) << 3) + (g & 1) * 4;  // u16 units
      uint2 val; val.x = w0; val.y = w1;
      *(uint2*)&pw[off] = val;
    }
    // ---- PV: O^T += V^T-frag x P^T-frag, 4 key-subtiles of 32 ----
#pragma unroll
    for (int kk = 0; kk < 4; ++kk) {
      int off = lr * 128 + (((kk * 4 + g) ^ (lr & 7)) << 3);
      bf16x8 pb = __builtin_bit_cast(bf16x8, *(const u16x8*)&pw[off]);
      bf16x8 va = __builtin_bit_cast(bf16x8, *(const u16x8*)&sVT[off]);
      acc = MFMA16(va, pb, acc);
    }
  }

  // ---- epilogue: lane owns q=lr, d = 4g + reg ----
  float inv = 1.0f / lrun;
  size_t o = ((size_t)b * N_ + qrow) * C_ + h * HD_ + 4 * g;
  u16x4 vh, vl;
#pragma unroll
  for (int r = 0; r < 4; ++r) {
    u16 hh, ll; splitf(acc[r] * inv, hh, ll);
    vh[r] = hh; vl[r] = ll;
  }
  *(u16x4*)&oh[o] = vh;
  *(u16x4*)&ol[o] = vl;
}

// ---------------------------------------------------------------------------
extern "C" void kernel_launch(void* const* d_in, const int* in_sizes, int n_in,
                              void* d_out, int out_size, void* d_ws, size_t ws_size,
                              hipStream_t stream) {
  const float* x     = (const float*)d_in[0];
  const float* w1    = (const float*)d_in[1];
  const float* b1    = (const float*)d_in[2];
  const float* w2    = (const float*)d_in[3];
  const float* b2    = (const float*)d_in[4];
  const float* w3    = (const float*)d_in[5];
  const float* b3    = (const float*)d_in[6];
  const float* w_out = (const float*)d_in[7];
  float* out = (float*)d_out;

  // ---- workspace layout (byte offsets) ----
  char* ws = (char*)d_ws;
  u16* XPH = (u16*)(ws + 0);                    //  7,102,464 B
  u16* XPL = (u16*)(ws + 7102464);
  u16* W1H = (u16*)(ws + 14204928);             //  2,654,208 B
  u16* W1L = (u16*)(ws + 16859136);
  u16* W2H = (u16*)(ws + 19513344);             //  1,179,648 B
  u16* W2L = (u16*)(ws + 20692992);
  u16* W3H = (u16*)(ws + 21872640);             //    884,736 B
  u16* W3L = (u16*)(ws + 22757376);
  u16* WOH = (u16*)(ws + 23642112);             //     73,728 B
  u16* WOL = (u16*)(ws + 23715840);
  // Region A @23,789,568: a1 hi/lo -> a3 f32 -> o hi/lo
  u16*   A1H = (u16*)(ws + 23789568);
  u16*   A1L = (u16*)(ws + 48955392);
  float* A3  = (float*)(ws + 23789568);         // a1 dead
  u16*   OH  = (u16*)(ws + 23789568);           // a3 dead after gather
  u16*   OL  = (u16*)(ws + 36372480);
  // Region B @74,121,216: a2 hi/lo -> QH/QL/KH/KL/VB u16 (6,291,456 B each)
  u16*   A2H = (u16*)(ws + 74121216);
  u16*   A2L = (u16*)(ws + 99287040);
  u16*   QHb = (u16*)(ws + 74121216);           // a2 dead
  u16*   QLb = (u16*)(ws + 80412672);
  u16*   KHb = (u16*)(ws + 86704128);
  u16*   KLb = (u16*)(ws + 92995584);
  u16*   VBb = (u16*)(ws + 99287040);
  // total: 124,452,864 B

  // ---- pack inputs to bf16 hi/lo ----
  pack_x_kernel<<<dim3(1734), 256, 0, stream>>>(x, XPH, XPL);
  pack_w1_kernel<<<dim3(576), 256, 0, stream>>>(w1, W1H, W1L);
  pack_gen_kernel<<<dim3(288), 256, 0, stream>>>(w2, W2H, W2L, 73728);
  pack_gen_kernel<<<dim3(216), 256, 0, stream>>>(w3, W3H, W3L, 55296);
  pack_gen_kernel<<<dim3(18), 256, 0, stream>>>(w_out, WOH, WOL, 4608);

  // ---- main pipeline ----
  conv_mfma_kernel<<<dim3(8, 6, 16), 256, 0, stream>>>(XPH, XPL, W1H, W1L, b1, A1H, A1L);
  gemm_mfma_kernel<0, 128><<<dim3(8, 6, 16), 256, 0, stream>>>(
      W2H, W2L, b2, A1H, A1L, A2H, A2L, HID_, HID_);
  gemm_mfma_kernel<1, 64><<<dim3(8, 9, 16), 256, 0, stream>>>(
      W3H, W3L, b3, A2H, A2L, A3, nullptr, C3_, HID_);
  qkv_gather_kernel<<<dim3(12288), 256, 0, stream>>>(A3, x, QHb, QLb, KHb, KLb, VBb);
  attn_mfma_kernel<<<dim3(16, 12, 16), 256, 0, stream>>>(QHb, QLb, KHb, KLb, VBb, OH, OL);
  gemm_mfma_kernel<2, 64><<<dim3(8, 3, 16), 256, 0, stream>>>(
      WOH, WOL, nullptr, OH, OL, out, nullptr, C_, C_);
}

// Round 12
// 468.650 us; speedup vs baseline: 1.2954x; 1.0299x over previous
//
#include <hip/hip_runtime.h>
#include <hip/hip_bf16.h>
#include <math.h>

// Problem constants
#define B_   16
#define P_   32
#define N_   1024
#define C_   192
#define H_   12
#define HD_  16
#define HID_ 768
#define C3_  576
#define SCALE_ 0.25f

using u16 = unsigned short;
typedef __bf16 bf16x8 __attribute__((ext_vector_type(8)));
typedef float f32x4 __attribute__((ext_vector_type(4)));
typedef u16 u16x8 __attribute__((ext_vector_type(8)));
typedef u16 u16x4 __attribute__((ext_vector_type(4)));

#define MFMA16(a, b, c) __builtin_amdgcn_mfma_f32_16x16x32_bf16((a), (b), (c), 0, 0, 0)

__device__ __forceinline__ int swz(int r) { return (r + (r >> 2)) & 3; }

__device__ __forceinline__ void splitf(float v, u16& h, u16& l) {
  union { __hip_bfloat16 b; u16 u; } c1, c2;
  c1.b = __float2bfloat16(v);
  float hv = __bfloat162float(c1.b);
  c2.b = __float2bfloat16(v - hv);
  h = c1.u; l = c2.u;
}

__device__ __forceinline__ u16 bfbits(float v) {
  union { __hip_bfloat16 b; u16 u; } c; c.b = __float2bfloat16(v); return c.u;
}

// LDS fragment read: tile stored as [row][32 k] u16, 64B rows, chunk-XOR swizzle.
__device__ __forceinline__ bf16x8 ldfrag(const u16* base, int row, int g) {
  return __builtin_bit_cast(bf16x8,
      *(const u16x8*)(base + row * 32 + ((g ^ swz(row)) << 3)));
}

// ---------------------------------------------------------------------------
// Pack x -> zero-padded 34x34 image, [b][pad_pixel][192ch] bf16 hi/lo.
__global__ __launch_bounds__(256) void pack_x_kernel(const float* __restrict__ x,
                                                     u16* __restrict__ xph,
                                                     u16* __restrict__ xpl) {
  int tid = blockIdx.x * 256 + threadIdx.x;   // 16*1156*24 = 443904 total
  int b = tid / 27744;
  int r = tid - b * 27744;
  int pp = r / 24;
  int cg = (r - pp * 24) * 8;
  int pr = pp / 34, pc = pp - pr * 34;
  float v[8] = {0.f, 0.f, 0.f, 0.f, 0.f, 0.f, 0.f, 0.f};
  if (pr >= 1 && pr <= 32 && pc >= 1 && pc <= 32) {
    const float* src = x + ((size_t)b * N_ + (pr - 1) * 32 + (pc - 1)) * C_ + cg;
    float4 v0 = *(const float4*)src;
    float4 v1 = *(const float4*)(src + 4);
    v[0] = v0.x; v[1] = v0.y; v[2] = v0.z; v[3] = v0.w;
    v[4] = v1.x; v[5] = v1.y; v[6] = v1.z; v[7] = v1.w;
  }
  u16x8 vh, vl;
#pragma unroll
  for (int i = 0; i < 8; ++i) { u16 h, l; splitf(v[i], h, l); vh[i] = h; vl[i] = l; }
  size_t o = ((size_t)b * 1156 + pp) * C_ + cg;
  *(u16x8*)&xph[o] = vh;
  *(u16x8*)&xpl[o] = vl;
}

// Pack w1 [768][192][3][3] -> [tap][768][192] hi/lo
__global__ __launch_bounds__(256) void pack_w1_kernel(const float* __restrict__ w1,
                                                      u16* __restrict__ w1h,
                                                      u16* __restrict__ w1l) {
  int tid = blockIdx.x * 256 + threadIdx.x;   // 147456
  int oc = tid / C_, ic = tid - oc * C_;
  const float* src = w1 + ((size_t)oc * C_ + ic) * 9;
#pragma unroll
  for (int t9 = 0; t9 < 9; ++t9) {
    u16 h, l; splitf(src[t9], h, l);
    size_t o = (size_t)t9 * (HID_ * C_) + oc * C_ + ic;
    w1h[o] = h; w1l[o] = l;
  }
}

// Generic elementwise pack
__global__ __launch_bounds__(256) void pack_gen_kernel(const float* __restrict__ src,
                                                       u16* __restrict__ dh,
                                                       u16* __restrict__ dl, int n8) {
  int tid = blockIdx.x * 256 + threadIdx.x;
  if (tid >= n8) return;
  const float* s = src + (size_t)tid * 8;
  float4 v0 = *(const float4*)s;
  float4 v1 = *(const float4*)(s + 4);
  float v[8] = {v0.x, v0.y, v0.z, v0.w, v1.x, v1.y, v1.z, v1.w};
  u16x8 vh, vl;
#pragma unroll
  for (int i = 0; i < 8; ++i) { u16 h, l; splitf(v[i], h, l); vh[i] = h; vl[i] = l; }
  *(u16x8*)&dh[(size_t)tid * 8] = vh;
  *(u16x8*)&dl[(size_t)tid * 8] = vl;
}

// ---------------------------------------------------------------------------
// conv3x3 implicit GEMM. (R11 measured-good form, unchanged.)
__global__ __launch_bounds__(256, 3) void conv_mfma_kernel(
    const u16* __restrict__ xph, const u16* __restrict__ xpl,
    const u16* __restrict__ w1h, const u16* __restrict__ w1l,
    const float* __restrict__ b1, u16* __restrict__ a1h, u16* __restrict__ a1l) {
  __shared__ u16 sH[2][204 * 32];   // halo pixels hi/lo (25.5 KB)
  __shared__ u16 sA[2][128 * 32];   // weights [plane], single buffer (16 KB)
  int t = threadIdx.x;
  int n0 = blockIdx.x * 128, oc0 = blockIdx.y * 128, b = blockIdx.z;
  int row0 = blockIdx.x * 4;        // first image row of this px-tile
  int wid = t >> 6, lane = t & 63;
  int wm = wid >> 1, wn = wid & 1;
  int g = lane >> 4, lr = lane & 15;
  int r0s = t >> 2, p0s = t & 3;
  int r1s = 64 + (t >> 2);
  size_t ga0 = (size_t)(oc0 + r0s) * C_ + p0s * 8;
  size_t ga1 = (size_t)(oc0 + r1s) * C_ + p0s * 8;
  int la0 = r0s * 32 + ((p0s ^ swz(r0s)) << 3);
  int la1 = r1s * 32 + ((p0s ^ swz(r1s)) << 3);
  f32x4 acc[4][4] = {};

  for (int ks = 0; ks < 6; ++ks) {
    int kk = ks * 32;
    __syncthreads();
    for (int c = t; c < 1632; c += 256) {
      int plane = c >= 816;
      int rem = c - plane * 816;
      int px = rem >> 2, p = rem & 3;
      size_t gidx = ((size_t)b * 1156 + row0 * 34 + px) * C_ + kk + p * 8;
      const u16* src = plane ? xpl : xph;
      *(u16x8*)&sH[plane][px * 32 + ((p ^ swz(px)) << 3)] = *(const u16x8*)&src[gidx];
    }
    {
      const u16* wth = w1h + kk;
      const u16* wtl = w1l + kk;
      *(u16x8*)&sA[0][la0] = *(const u16x8*)&wth[ga0];
      *(u16x8*)&sA[0][la1] = *(const u16x8*)&wth[ga1];
      *(u16x8*)&sA[1][la0] = *(const u16x8*)&wtl[ga0];
      *(u16x8*)&sA[1][la1] = *(const u16x8*)&wtl[ga1];
    }
    __syncthreads();

    for (int tap = 0; tap < 9; ++tap) {
      u16x8 rh0, rh1, rl0, rl1;
      if (tap < 8) {
        const u16* wth = w1h + (size_t)(tap + 1) * (HID_ * C_) + kk;
        const u16* wtl = w1l + (size_t)(tap + 1) * (HID_ * C_) + kk;
        rh0 = *(const u16x8*)&wth[ga0];
        rh1 = *(const u16x8*)&wth[ga1];
        rl0 = *(const u16x8*)&wtl[ga0];
        rl1 = *(const u16x8*)&wtl[ga1];
      }
      int dy = tap / 3, dx = tap - dy * 3;
      bf16x8 ah[4], al[4], bh[4], bl[4];
#pragma unroll
      for (int mf = 0; mf < 4; ++mf) {
        int row = wm * 64 + mf * 16 + lr;
        ah[mf] = ldfrag(&sA[0][0], row, g);
        al[mf] = ldfrag(&sA[1][0], row, g);
      }
#pragma unroll
      for (int nf = 0; nf < 4; ++nf) {
        int lp = wn * 64 + nf * 16 + lr;
        int hpx = ((lp >> 5) + dy) * 34 + (lp & 31) + dx;
        bh[nf] = ldfrag(&sH[0][0], hpx, g);
        bl[nf] = ldfrag(&sH[1][0], hpx, g);
      }
#pragma unroll
      for (int mf = 0; mf < 4; ++mf)
#pragma unroll
        for (int nf = 0; nf < 4; ++nf) {
          acc[mf][nf] = MFMA16(ah[mf], bh[nf], acc[mf][nf]);
          acc[mf][nf] = MFMA16(al[mf], bh[nf], acc[mf][nf]);
          acc[mf][nf] = MFMA16(ah[mf], bl[nf], acc[mf][nf]);
        }
      if (tap < 8) {
        __syncthreads();
        *(u16x8*)&sA[0][la0] = rh0;
        *(u16x8*)&sA[0][la1] = rh1;
        *(u16x8*)&sA[1][la0] = rl0;
        *(u16x8*)&sA[1][la1] = rl1;
        __syncthreads();
      }
    }
  }
#pragma unroll
  for (int mf = 0; mf < 4; ++mf)
#pragma unroll
    for (int nf = 0; nf < 4; ++nf) {
      int pix = n0 + wn * 64 + nf * 16 + lr;
      int oc = oc0 + wm * 64 + mf * 16 + g * 4;
      size_t oidx = ((size_t)b * N_ + pix) * HID_ + oc;
      u16x4 vh, vl;
#pragma unroll
      for (int r = 0; r < 4; ++r) {
        float v = acc[mf][nf][r] + b1[oc + r];
        v = v > 0.f ? v : 0.f;
        u16 h, l; splitf(v, h, l);
        vh[r] = h; vl[r] = l;
      }
      *(u16x4*)&a1h[oidx] = vh;
      *(u16x4*)&a1l[oidx] = vl;
    }
}

// ---------------------------------------------------------------------------
// Generic MFMA GEMM over [pixel][IC] activations. Block tile MT x 128px,
// 4 waves (2m x 2n), wave tile (MT/2) x 64. grid (128/128, OC/MT, 16).
// ACT: 0 relu->bf16 hi/lo, 1 sigmoid->f32, 2 none->f32.
template <int ACT, int MT>
__global__ __launch_bounds__(256) void gemm_mfma_kernel(
    const u16* __restrict__ Wh, const u16* __restrict__ Wl,
    const float* __restrict__ bias,
    const u16* __restrict__ inh, const u16* __restrict__ inl,
    void* __restrict__ out0, void* __restrict__ out1, int OC, int IC) {
  constexpr int MF = MT / 32;
  __shared__ u16 sA[2][MT * 32];
  __shared__ u16 sB[2][128 * 32];
  int t = threadIdx.x;
  int n0 = blockIdx.x * 128, oc0 = blockIdx.y * MT, b = blockIdx.z;
  int wid = t >> 6, lane = t & 63;
  int wm = wid >> 1, wn = wid & 1;
  int g = lane >> 4, lr = lane & 15;
  const u16* inbh = inh + (size_t)b * N_ * IC;
  const u16* inbl = inl + (size_t)b * N_ * IC;
  f32x4 acc[MF][4] = {};

  for (int ks = 0; ks < IC / 32; ++ks) {
    int kk = ks * 32;
    __syncthreads();
    for (int c = t; c < MT * 4; c += 256) {
      int r = c >> 2, p = c & 3;
      size_t gidx = (size_t)(oc0 + r) * IC + kk + p * 8;
      int lidx = r * 32 + ((p ^ swz(r)) << 3);
      *(u16x8*)&sA[0][lidx] = *(const u16x8*)&Wh[gidx];
      *(u16x8*)&sA[1][lidx] = *(const u16x8*)&Wl[gidx];
    }
#pragma unroll
    for (int i = 0; i < 2; ++i) {
      int c = t + i * 256;
      int r = c >> 2, p = c & 3;
      size_t gidx = (size_t)(n0 + r) * IC + kk + p * 8;
      int lidx = r * 32 + ((p ^ swz(r)) << 3);
      *(u16x8*)&sB[0][lidx] = *(const u16x8*)&inbh[gidx];
      *(u16x8*)&sB[1][lidx] = *(const u16x8*)&inbl[gidx];
    }
    __syncthreads();
    bf16x8 ah[MF], al[MF], bh[4], bl[4];
#pragma unroll
    for (int mf = 0; mf < MF; ++mf) {
      int row = wm * (MT / 2) + mf * 16 + lr;
      ah[mf] = ldfrag(&sA[0][0], row, g);
      al[mf] = ldfrag(&sA[1][0], row, g);
    }
#pragma unroll
    for (int nf = 0; nf < 4; ++nf) {
      int row = wn * 64 + nf * 16 + lr;
      bh[nf] = ldfrag(&sB[0][0], row, g);
      bl[nf] = ldfrag(&sB[1][0], row, g);
    }
#pragma unroll
    for (int mf = 0; mf < MF; ++mf)
#pragma unroll
      for (int nf = 0; nf < 4; ++nf) {
        acc[mf][nf] = MFMA16(ah[mf], bh[nf], acc[mf][nf]);
        acc[mf][nf] = MFMA16(al[mf], bh[nf], acc[mf][nf]);
        acc[mf][nf] = MFMA16(ah[mf], bl[nf], acc[mf][nf]);
      }
  }
#pragma unroll
  for (int mf = 0; mf < MF; ++mf)
#pragma unroll
    for (int nf = 0; nf < 4; ++nf) {
      int pix = n0 + wn * 64 + nf * 16 + lr;
      int oc = oc0 + wm * (MT / 2) + mf * 16 + g * 4;
      size_t oidx = ((size_t)b * N_ + pix) * OC + oc;
      if constexpr (ACT == 0) {
        u16x4 vh, vl;
#pragma unroll
        for (int r = 0; r < 4; ++r) {
          float v = acc[mf][nf][r] + bias[oc + r];
          v = v > 0.f ? v : 0.f;
          u16 h, l; splitf(v, h, l);
          vh[r] = h; vl[r] = l;
        }
        *(u16x4*)&((u16*)out0)[oidx] = vh;
        *(u16x4*)&((u16*)out1)[oidx] = vl;
      } else if constexpr (ACT == 1) {
        float4 res;
        float r0 = acc[mf][nf][0] + bias[oc + 0];
        float r1 = acc[mf][nf][1] + bias[oc + 1];
        float r2 = acc[mf][nf][2] + bias[oc + 2];
        float r3 = acc[mf][nf][3] + bias[oc + 3];
        res.x = 1.f / (1.f + __expf(-r0)); res.y = 1.f / (1.f + __expf(-r1));
        res.z = 1.f / (1.f + __expf(-r2)); res.w = 1.f / (1.f + __expf(-r3));
        *(float4*)&((float*)out0)[oidx] = res;
      } else {
        float4 res;
        res.x = acc[mf][nf][0]; res.y = acc[mf][nf][1];
        res.z = acc[mf][nf][2]; res.w = acc[mf][nf][3];
        *(float4*)&((float*)out0)[oidx] = res;
      }
    }
}

// ---------------------------------------------------------------------------
// qkv gather: a3 [b][pixel][576] f32 -> QH/QL (hi/lo) + KB/VB (single bf16)
// in [b,h,n,16] u16 layout. Same flat-index scramble as reference.
__global__ __launch_bounds__(256) void qkv_gather_kernel(const float* __restrict__ a3,
                                                         const float* __restrict__ x,
                                                         u16* __restrict__ qh,
                                                         u16* __restrict__ ql,
                                                         u16* __restrict__ kb,
                                                         u16* __restrict__ vb) {
  int idx = blockIdx.x * 256 + threadIdx.x;
  int b = idx / 196608;
  int gg = idx - b * 196608;
  int m = gg & 1023, cc = gg >> 10;
  int j = m * 192 + cc;
  float y = x[((size_t)b * N_ + (j & 1023)) * C_ + (j >> 10)];
  int n2 = gg / 192;
  int hd = gg - n2 * 192;
  size_t out_idx = (((size_t)b * H_ + (hd >> 4)) * N_ + n2) * HD_ + (hd & 15);
  const float* a3b = a3 + (size_t)b * (C3_ * N_);
  int jk = j + 196608, jv = j + 393216;
  int nq = j / 576,  chq = j - nq * 576;
  int nk = jk / 576, chk = jk - nk * 576;
  int nv = jv / 576, chv = jv - nv * 576;
  float aq = a3b[(size_t)nq * C3_ + chq];
  float ak = a3b[(size_t)nk * C3_ + chk];
  float av = a3b[(size_t)nv * C3_ + chv];
  u16 hh, ll;
  splitf(aq * y * SCALE_, hh, ll); qh[out_idx] = hh; ql[out_idx] = ll;
  kb[out_idx] = bfbits(ak * y);
  vb[out_idx] = bfbits(av * y);
}

// ---------------------------------------------------------------------------
// MFMA flash attention. grid (8 qtiles, 12 h, 16 b), 4 waves; each wave owns
// TWO 16-q subtiles (128 q-rows/block) processed sequentially, sharing the
// staged K/V chunk. K single bf16 (2-mfma QK: kf*ql + kf*qh); Q hi/lo.
// Swapped QK^T (S^T[key,q], d padded 16->32) and swapped PV (O^T[d,q]).
__global__ __launch_bounds__(256) void attn_mfma_kernel(
    const u16* __restrict__ QH, const u16* __restrict__ QL,
    const u16* __restrict__ KB, const u16* __restrict__ VB,
    u16* __restrict__ oh, u16* __restrict__ ol) {
  __shared__ u16 sK[128 * 32];    // [key][32 d-padded] swizzled (8KB)
  __shared__ u16 sVT[16 * 128];   // [d][128 keys], 16B-chunk XOR swizzle (4KB)
  __shared__ u16 sP[4][16 * 128]; // per-wave P^T bounce [q][128 keys] (16KB)
  int t = threadIdx.x;
  int qt = blockIdx.x, h = blockIdx.y, b = blockIdx.z;
  int wid = t >> 6, lane = t & 63;
  int lr = lane & 15, g = lane >> 4;
  size_t base = ((size_t)(b * H_ + h)) * (N_ * HD_);

  // zero the d=16..31 pad chunks of sK once (one slot per thread)
  {
    int r = t >> 1, gg = 2 + (t & 1);
    u16x8 z = {};
    *(u16x8*)(sK + r * 32 + ((gg ^ swz(r)) << 3)) = z;
  }

  // Q fragments for both subtiles: lane lr = q-col, g = d-slice (g>=2 zero)
  bf16x8 qfh[2] = {}, qfl[2] = {};
#pragma unroll
  for (int s = 0; s < 2; ++s) {
    if (g < 2) {
      int qrow = qt * 128 + s * 64 + wid * 16 + lr;
      size_t qi = base + (size_t)qrow * HD_ + g * 8;
      qfh[s] = __builtin_bit_cast(bf16x8, *(const u16x8*)&QH[qi]);
      qfl[s] = __builtin_bit_cast(bf16x8, *(const u16x8*)&QL[qi]);
    }
  }

  f32x4 acc[2] = {};
  float mrun[2] = {-1e30f, -1e30f};
  float lrun[2] = {0.f, 0.f};
  u16* pw = &sP[wid][0];

  for (int ch = 0; ch < 8; ++ch) {
    int key0 = ch * 128;
    __syncthreads();
    // ---- stage K chunk: 128 keys x 16 real d, one u16x8 per thread ----
    {
      int r = t >> 1, gg2 = t & 1;
      *(u16x8*)&sK[r * 32 + ((gg2 ^ swz(r)) << 3)] =
          *(const u16x8*)&KB[base + (size_t)(key0 + r) * HD_ + gg2 * 8];
    }
    // ---- stage V^T: [d][128 keys] via u16 scatter ----
#pragma unroll
    for (int i = 0; i < 2; ++i) {
      int e = i * 256 + t;
      int key = e >> 2, d0 = (e & 3) * 4;
      u16x4 vv = *(const u16x4*)&VB[base + (size_t)(key0 + key) * HD_ + d0];
#pragma unroll
      for (int jj = 0; jj < 4; ++jj) {
        int d = d0 + jj;
        sVT[d * 128 + (((key >> 3) ^ (d & 7)) << 3) + (key & 7)] = vv[jj];
      }
    }
    __syncthreads();

#pragma unroll
    for (int s = 0; s < 2; ++s) {
      // ---- QK^T: 8 key-subtiles, S^T[key,q], K single + Q hi/lo (2 mfma) ----
      f32x4 st[8];
#pragma unroll
      for (int t8 = 0; t8 < 8; ++t8) {
        bf16x8 kf = ldfrag(sK, t8 * 16 + lr, g);
        f32x4 sv = {};
        sv = MFMA16(kf, qfl[s], sv);
        sv = MFMA16(kf, qfh[s], sv);
        st[t8] = sv;
      }

      // ---- online softmax: lane owns q=lr; keys split over 4 lanes (g) ----
      float cmax = -1e30f;
#pragma unroll
      for (int t8 = 0; t8 < 8; ++t8)
#pragma unroll
        for (int r = 0; r < 4; ++r) cmax = fmaxf(cmax, st[t8][r]);
      cmax = fmaxf(cmax, __shfl_xor(cmax, 16));
      cmax = fmaxf(cmax, __shfl_xor(cmax, 32));
      float mnew = fmaxf(mrun[s], cmax);
      float corr = __expf(mrun[s] - mnew);
      float p[32];
      float psum = 0.f;
#pragma unroll
      for (int t8 = 0; t8 < 8; ++t8)
#pragma unroll
        for (int r = 0; r < 4; ++r) {
          float pv = __expf(st[t8][r] - mnew);
          p[t8 * 4 + r] = pv; psum += pv;
        }
      psum += __shfl_xor(psum, 16);
      psum += __shfl_xor(psum, 32);
      lrun[s] = lrun[s] * corr + psum;
      mrun[s] = mnew;
#pragma unroll
      for (int r = 0; r < 4; ++r) acc[s][r] *= corr;

      // ---- pack P to bf16, bounce via per-wave LDS to re-group keys ----
#pragma unroll
      for (int t8 = 0; t8 < 8; ++t8) {
        unsigned w0 = (unsigned)bfbits(p[t8 * 4 + 0]) | ((unsigned)bfbits(p[t8 * 4 + 1]) << 16);
        unsigned w1 = (unsigned)bfbits(p[t8 * 4 + 2]) | ((unsigned)bfbits(p[t8 * 4 + 3]) << 16);
        int c = 2 * t8 + (g >> 1);
        int off = lr * 128 + ((c ^ (lr & 7)) << 3) + (g & 1) * 4;  // u16 units
        uint2 val; val.x = w0; val.y = w1;
        *(uint2*)&pw[off] = val;
      }
      // ---- PV: O^T += V^T-frag x P^T-frag, 4 key-subtiles of 32 ----
#pragma unroll
      for (int kk = 0; kk < 4; ++kk) {
        int off = lr * 128 + (((kk * 4 + g) ^ (lr & 7)) << 3);
        bf16x8 pb = __builtin_bit_cast(bf16x8, *(const u16x8*)&pw[off]);
        bf16x8 va = __builtin_bit_cast(bf16x8, *(const u16x8*)&sVT[off]);
        acc[s] = MFMA16(va, pb, acc[s]);
      }
    }
  }

  // ---- epilogue: lane owns q=lr, d = 4g + reg ----
#pragma unroll
  for (int s = 0; s < 2; ++s) {
    float inv = 1.0f / lrun[s];
    int qrow = qt * 128 + s * 64 + wid * 16 + lr;
    size_t o = ((size_t)b * N_ + qrow) * C_ + h * HD_ + 4 * g;
    u16x4 vh, vl;
#pragma unroll
    for (int r = 0; r < 4; ++r) {
      u16 hh, ll; splitf(acc[s][r] * inv, hh, ll);
      vh[r] = hh; vl[r] = ll;
    }
    *(u16x4*)&oh[o] = vh;
    *(u16x4*)&ol[o] = vl;
  }
}

// ---------------------------------------------------------------------------
extern "C" void kernel_launch(void* const* d_in, const int* in_sizes, int n_in,
                              void* d_out, int out_size, void* d_ws, size_t ws_size,
                              hipStream_t stream) {
  const float* x     = (const float*)d_in[0];
  const float* w1    = (const float*)d_in[1];
  const float* b1    = (const float*)d_in[2];
  const float* w2    = (const float*)d_in[3];
  const float* b2    = (const float*)d_in[4];
  const float* w3    = (const float*)d_in[5];
  const float* b3    = (const float*)d_in[6];
  const float* w_out = (const float*)d_in[7];
  float* out = (float*)d_out;

  // ---- workspace layout (byte offsets) ----
  char* ws = (char*)d_ws;
  u16* XPH = (u16*)(ws + 0);                    //  7,102,464 B
  u16* XPL = (u16*)(ws + 7102464);
  u16* W1H = (u16*)(ws + 14204928);             //  2,654,208 B
  u16* W1L = (u16*)(ws + 16859136);
  u16* W2H = (u16*)(ws + 19513344);             //  1,179,648 B
  u16* W2L = (u16*)(ws + 20692992);
  u16* W3H = (u16*)(ws + 21872640);             //    884,736 B
  u16* W3L = (u16*)(ws + 22757376);
  u16* WOH = (u16*)(ws + 23642112);             //     73,728 B
  u16* WOL = (u16*)(ws + 23715840);
  // Region A @23,789,568: a1 hi/lo -> a3 f32 -> o hi/lo
  u16*   A1H = (u16*)(ws + 23789568);
  u16*   A1L = (u16*)(ws + 48955392);
  float* A3  = (float*)(ws + 23789568);         // a1 dead
  u16*   OH  = (u16*)(ws + 23789568);           // a3 dead after gather
  u16*   OL  = (u16*)(ws + 36372480);
  // Region B @74,121,216: a2 hi/lo -> QH/QL/KB/VB u16 (6,291,456 B each)
  u16*   A2H = (u16*)(ws + 74121216);
  u16*   A2L = (u16*)(ws + 99287040);
  u16*   QHb = (u16*)(ws + 74121216);           // a2 dead
  u16*   QLb = (u16*)(ws + 80412672);
  u16*   KBb = (u16*)(ws + 86704128);
  u16*   VBb = (u16*)(ws + 99287040);
  // total: 124,452,864 B

  // ---- pack inputs to bf16 hi/lo ----
  pack_x_kernel<<<dim3(1734), 256, 0, stream>>>(x, XPH, XPL);
  pack_w1_kernel<<<dim3(576), 256, 0, stream>>>(w1, W1H, W1L);
  pack_gen_kernel<<<dim3(288), 256, 0, stream>>>(w2, W2H, W2L, 73728);
  pack_gen_kernel<<<dim3(216), 256, 0, stream>>>(w3, W3H, W3L, 55296);
  pack_gen_kernel<<<dim3(18), 256, 0, stream>>>(w_out, WOH, WOL, 4608);

  // ---- main pipeline ----
  conv_mfma_kernel<<<dim3(8, 6, 16), 256, 0, stream>>>(XPH, XPL, W1H, W1L, b1, A1H, A1L);
  gemm_mfma_kernel<0, 128><<<dim3(8, 6, 16), 256, 0, stream>>>(
      W2H, W2L, b2, A1H, A1L, A2H, A2L, HID_, HID_);
  gemm_mfma_kernel<1, 96><<<dim3(8, 6, 16), 256, 0, stream>>>(
      W3H, W3L, b3, A2H, A2L, A3, nullptr, C3_, HID_);
  qkv_gather_kernel<<<dim3(12288), 256, 0, stream>>>(A3, x, QHb, QLb, KBb, VBb);
  attn_mfma_kernel<<<dim3(8, 12, 16), 256, 0, stream>>>(QHb, QLb, KBb, VBb, OH, OL);
  gemm_mfma_kernel<2, 64><<<dim3(8, 3, 16), 256, 0, stream>>>(
      WOH, WOL, nullptr, OH, OL, out, nullptr, C_, C_);
}